// Round 7
// baseline (1980.535 us; speedup 1.0000x reference)
//
#include <hip/hip_runtime.h>
#include <math.h>

#define BB 8
#define NN 2304
#define DD 768
#define DM 64
#define EPSF 1e-5f

typedef __attribute__((ext_vector_type(8))) short short8;   // 8 x bf16 bits (16 B)
typedef __attribute__((ext_vector_type(4))) short short4v;  // 4 x bf16 bits (8 B)
typedef __attribute__((ext_vector_type(4))) float f32x4;
typedef __attribute__((ext_vector_type(2))) unsigned int uint2v;

static __device__ __forceinline__ unsigned short f2b(float f) {
    unsigned u = __float_as_uint(f);
    unsigned r = u + 0x7FFFu + ((u >> 16) & 1u);
    return (unsigned short)(r >> 16);
}
static __device__ __forceinline__ float b2f(unsigned short h) {
    return __uint_as_float(((unsigned)h) << 16);
}
#define MFMA(a, b, c) __builtin_amdgcn_mfma_f32_16x16x32_bf16((a), (b), (c), 0, 0, 0)

// ---------- layer-0: fp32 x [B][N][D] -> split-bf16 transposed xT_hi/lo [B][D][N] ----
__global__ __launch_bounds__(256) void cvt_kernel(const float* __restrict__ xf,
                                                  unsigned short* __restrict__ xTh,
                                                  unsigned short* __restrict__ xTl) {
    __shared__ __align__(16) unsigned short Th[64][72];
    __shared__ __align__(16) unsigned short Tl[64][72];
    int t = threadIdx.x;
    int b = blockIdx.z;
    int n0 = blockIdx.x * 64, c0 = blockIdx.y * 64;
    int rr = t >> 4, cc = (t & 15) * 4;
    #pragma unroll
    for (int i = 0; i < 4; ++i) {
        int r = rr + i * 16;
        long idx = ((long)b * NN + n0 + r) * DD + c0 + cc;
        float4 v = *(const float4*)&xf[idx];
        unsigned short h0 = f2b(v.x), h1 = f2b(v.y), h2 = f2b(v.z), h3 = f2b(v.w);
        Th[cc + 0][r] = h0; Th[cc + 1][r] = h1; Th[cc + 2][r] = h2; Th[cc + 3][r] = h3;
        Tl[cc + 0][r] = f2b(v.x - b2f(h0));
        Tl[cc + 1][r] = f2b(v.y - b2f(h1));
        Tl[cc + 2][r] = f2b(v.z - b2f(h2));
        Tl[cc + 3][r] = f2b(v.w - b2f(h3));
    }
    __syncthreads();
    #pragma unroll
    for (int i = 0; i < 4; ++i) {
        int c = rr + i * 16;
        long idx = ((long)b * DD + c0 + c) * NN + n0 + cc;
        *(ushort4*)&xTh[idx] = *(const ushort4*)&Th[c][cc];
        *(ushort4*)&xTl[idx] = *(const ushort4*)&Tl[c][cc];
    }
}

// ---------- Wq fp32 [768][64] -> transposed split bf16 Wt_hi/lo [64][768] ----------
__global__ __launch_bounds__(256) void wqcvt_kernel(const float* __restrict__ Wq,
                                                    unsigned short* __restrict__ Wth,
                                                    unsigned short* __restrict__ Wtl) {
    int t = blockIdx.x * 256 + threadIdx.x;   // t < 768*64
    int d = t >> 6, m = t & 63;
    float v = Wq[t];
    unsigned short h = f2b(v);
    Wth[m * DD + d] = h;
    Wtl[m * DD + d] = f2b(v - b2f(h));
}

// zeroes stats (2 floats/row) + lsumG (1 float/row), contiguous: 3*BB*NN floats
__global__ __launch_bounds__(256) void zstats_kernel(float* __restrict__ stats) {
    stats[blockIdx.x * 256 + threadIdx.x] = 0.f;
}

// ---------- MFMA q-projection ------------------------------------------------------
__global__ __launch_bounds__(256) void proj_kernel(
        const unsigned short* __restrict__ Wth, const unsigned short* __restrict__ Wtl,
        const unsigned short* __restrict__ xTh, const unsigned short* __restrict__ xTl,
        const float* __restrict__ bq,
        unsigned short* __restrict__ qh, unsigned short* __restrict__ ql) {
    int t = threadIdx.x;
    int w = t >> 6, lane = t & 63, quad = lane >> 4, l15 = lane & 15;
    int n0 = blockIdx.x * 64, b = blockIdx.y;
    const unsigned short* xhb = xTh + (long)b * DD * NN;
    const unsigned short* xlb = xTl + (long)b * DD * NN;

    f32x4 accQ[4];
    #pragma unroll
    for (int nt = 0; nt < 4; ++nt) accQ[nt] = 0.f;

    for (int d0 = 0; d0 < DD; d0 += 32) {
        short8 ah = *(const short8*)&Wth[(w * 16 + l15) * DD + d0 + quad * 8];
        short8 al = *(const short8*)&Wtl[(w * 16 + l15) * DD + d0 + quad * 8];
        #pragma unroll
        for (int nt = 0; nt < 4; ++nt) {
            int row = n0 + nt * 16 + l15;
            short8 bh, bl;
            #pragma unroll
            for (int j = 0; j < 8; ++j) {
                long o = (long)(d0 + quad * 8 + j) * NN + row;
                bh[j] = (short)xhb[o];
                bl[j] = (short)xlb[o];
            }
            accQ[nt] = MFMA(ah, bh, accQ[nt]);
            accQ[nt] = MFMA(al, bh, accQ[nt]);
            accQ[nt] = MFMA(ah, bl, accQ[nt]);
        }
    }
    #pragma unroll
    for (int nt = 0; nt < 4; ++nt) {
        int row = n0 + nt * 16 + l15;
        #pragma unroll
        for (int e = 0; e < 4; ++e) {
            int qm = w * 16 + quad * 4 + e;
            float v = accQ[nt][e] + bq[qm];
            unsigned short h = f2b(v);
            long o = ((long)b * NN + row) * DM + qm;
            qh[o] = h;
            ql[o] = f2b(v - b2f(h));
        }
    }
}

// ============ kernel A: S = q.q^T, exp, split-bf16 pack -> global P ================
// P computed once per (b,row). Coalesced stores via wave-private swizzled LDS
// staging. grid (24, 12, gb): 192 keys/block (3 iters) for occupancy; 4 waves.
__global__ __launch_bounds__(256) void qk_kernel(
        const unsigned short* __restrict__ qhp, const unsigned short* __restrict__ qlp,
        unsigned short* __restrict__ Ph, unsigned short* __restrict__ Pl,
        float* __restrict__ lsumG, int bofs) {
    __shared__ __align__(16) unsigned short PHs[4 * 1536];  // [wave][48r x 32k]
    __shared__ __align__(16) unsigned short PLs[4 * 1536];
    const int t = threadIdx.x;
    const int w = t >> 6, lane = t & 63, quad = lane >> 4, l15 = lane & 15;
    const int sk = w & 1, sr = w >> 1;
    const int pbase = w * 1536;
    const int n0 = blockIdx.x * 96;
    const int k00 = blockIdx.y * 192;
    const int bL = blockIdx.z, b = bofs + bL;
    const unsigned short* qhb = qhp + (long)b * NN * DM;
    const unsigned short* qlb = qlp + (long)b * NN * DM;

    short8 bh[3][2], bl[3][2];
    #pragma unroll
    for (int rt = 0; rt < 3; ++rt)
        #pragma unroll
        for (int kc = 0; kc < 2; ++kc) {
            long o = (long)(n0 + sr * 48 + rt * 16 + l15) * DM + kc * 32 + quad * 8;
            bh[rt][kc] = *(const short8*)(qhb + o);
            bl[rt][kc] = *(const short8*)(qlb + o);
        }
    float lp[3] = {0.f, 0.f, 0.f};

    for (int k0 = k00; k0 < k00 + 192; k0 += 64) {
        #pragma unroll
        for (int kt = 0; kt < 2; ++kt) {
            long ao = (long)(k0 + sk * 32 + kt * 16 + l15) * DM + quad * 8;
            short8 qh0 = *(const short8*)(qhb + ao);
            short8 qh1 = *(const short8*)(qhb + ao + 32);
            short8 ql0 = *(const short8*)(qlb + ao);
            short8 ql1 = *(const short8*)(qlb + ao + 32);
            #pragma unroll
            for (int rt = 0; rt < 3; ++rt) {
                f32x4 s = 0.f;
                s = MFMA(qh0, bh[rt][0], s);
                s = MFMA(qh1, bh[rt][1], s);
                s = MFMA(ql0, bh[rt][0], s);
                s = MFMA(ql1, bh[rt][1], s);
                s = MFMA(qh0, bl[rt][0], s);
                s = MFMA(qh1, bl[rt][1], s);
                float p0 = __expf(s[0] * 0.125f);
                float p1 = __expf(s[1] * 0.125f);
                float p2 = __expf(s[2] * 0.125f);
                float p3 = __expf(s[3] * 0.125f);
                lp[rt] += (p0 + p1) + (p2 + p3);
                unsigned u0 = __float_as_uint(p0), u1 = __float_as_uint(p1);
                unsigned u2 = __float_as_uint(p2), u3 = __float_as_uint(p3);
                uint2v dh = { (u0 >> 16) | (u1 & 0xFFFF0000u),
                              (u2 >> 16) | (u3 & 0xFFFF0000u) };
                float r0 = p0 - __uint_as_float(u0 & 0xFFFF0000u);
                float r1 = p1 - __uint_as_float(u1 & 0xFFFF0000u);
                float r2 = p2 - __uint_as_float(u2 & 0xFFFF0000u);
                float r3 = p3 - __uint_as_float(u3 & 0xFFFF0000u);
                unsigned v0 = __float_as_uint(r0), v1 = __float_as_uint(r1);
                unsigned v2 = __float_as_uint(r2), v3 = __float_as_uint(r3);
                uint2v dl = { (v0 >> 16) | (v1 & 0xFFFF0000u),
                              (v2 >> 16) | (v3 & 0xFFFF0000u) };
                int rr = rt * 16 + l15;
                int ff = (((rr & 7) ^ (rr >> 3)) & 7) << 2;
                int ix = pbase + rr * 32 + ((kt * 16 + quad * 4) ^ ff);
                *(uint2v*)&PHs[ix] = dh;
                *(uint2v*)&PLs[ix] = dl;
            }
        }
        // readback (undo swizzle) + coalesced 16B stores: 4 lanes = 64B per row
        #pragma unroll
        for (int r = 0; r < 3; ++r) {
            int c = r * 64 + lane;          // 192 chunks = 48 rows x 4 segs
            int rr = c >> 2, s = c & 3;
            int ff = (((rr & 7) ^ (rr >> 3)) & 7) << 2;
            int i0 = pbase + rr * 32 + ((s * 8) ^ ff);
            int i1 = pbase + rr * 32 + ((s * 8 + 4) ^ ff);
            short4v h0 = *(const short4v*)&PHs[i0];
            short4v h1 = *(const short4v*)&PHs[i1];
            short4v l0 = *(const short4v*)&PLs[i0];
            short4v l1 = *(const short4v*)&PLs[i1];
            short8 hh = __builtin_shufflevector(h0, h1, 0, 1, 2, 3, 4, 5, 6, 7);
            short8 ll = __builtin_shufflevector(l0, l1, 0, 1, 2, 3, 4, 5, 6, 7);
            long po = ((long)bL * NN + n0 + sr * 48 + rr) * NN + k0 + sk * 32 + s * 8;
            *(short8*)&Ph[po] = hh;
            *(short8*)&Pl[po] = ll;
        }
    }
    #pragma unroll
    for (int rt = 0; rt < 3; ++rt) {
        float v = lp[rt];
        v += __shfl_xor(v, 16); v += __shfl_xor(v, 32);
        if (lane < 16)
            atomicAdd(&lsumG[(long)b * NN + n0 + sr * 48 + rt * 16 + l15], v);
    }
}

// ============ kernel B variant 1: pv_stream — pure register streaming GEMM =========
// NO LDS, NO barriers, NO inline asm: X and P fragments stream global->VGPR with a
// named A/B register double-buffer; the COMPILER inserts counted vmcnt for the
// register dependencies (R6's inline-asm vmcnt forced a conservative drain -> 204us).
// Waves fully independent; 96c x 96n block, wave (wc,wr) owns 48x48.
__global__ __launch_bounds__(256) void pv_stream(
        const unsigned short* __restrict__ Ph, const unsigned short* __restrict__ Pl,
        const unsigned short* __restrict__ xTh, const unsigned short* __restrict__ xTl,
        const float* __restrict__ lsumG, float* __restrict__ OT,
        float* __restrict__ stats, int bofs) {
    const int t = threadIdx.x;
    const int w = t >> 6, lane = t & 63, quad = lane >> 4, l15 = lane & 15;
    const int wc = w & 1, wr = w >> 1;
    // XCD-clustered block mapping (same as pv_lds)
    const int phys = blockIdx.x;
    const int gc = phys & 7;
    const int inner = phys >> 3;
    const int m = inner & 7;
    const int g = ((inner >> 3) << 3) + gc;
    const int cb = m * 96;
    const int n0 = (g % 24) * 96;
    const int bL = g / 24, b = bofs + bL;
    const unsigned short* xhb = xTh + (long)b * DD * NN;
    const unsigned short* xlb = xTl + (long)b * DD * NN;
    const unsigned short* phb = Ph + (long)bL * NN * NN;
    const unsigned short* plb = Pl + (long)bL * NN * NN;

    // per-lane row base pointers (k added per phase)
    const unsigned short* xp[3];
    const unsigned short* pp[3];
    #pragma unroll
    for (int ct = 0; ct < 3; ++ct)
        xp[ct] = xhb + (long)(cb + wc * 48 + ct * 16 + l15) * NN + quad * 8;
    #pragma unroll
    for (int nt = 0; nt < 3; ++nt)
        pp[nt] = phb + (long)(n0 + wr * 48 + nt * 16 + l15) * NN + quad * 8;
    const long hlX = (long)(xlb - xhb);   // uniform hi->lo offset
    const long hlP = (long)(plb - phb);

    f32x4 acc[3][3];
    #pragma unroll
    for (int ct = 0; ct < 3; ++ct)
        #pragma unroll
        for (int nt = 0; nt < 3; ++nt) acc[ct][nt] = 0.f;

#define LOADF(XH_, XL_, PH_, PL_, K_) do {                                         \
    _Pragma("unroll")                                                              \
    for (int ct = 0; ct < 3; ++ct) {                                               \
        XH_[ct] = *(const short8*)(xp[ct] + (K_));                                 \
        XL_[ct] = *(const short8*)(xp[ct] + hlX + (K_));                           \
    }                                                                              \
    _Pragma("unroll")                                                              \
    for (int nt = 0; nt < 3; ++nt) {                                               \
        PH_[nt] = *(const short8*)(pp[nt] + (K_));                                 \
        PL_[nt] = *(const short8*)(pp[nt] + hlP + (K_));                           \
    }                                                                              \
} while (0)

#define COMP(XH_, XL_, PH_, PL_) do {                                              \
    _Pragma("unroll")                                                              \
    for (int ct = 0; ct < 3; ++ct) {                                               \
        _Pragma("unroll")                                                          \
        for (int nt = 0; nt < 3; ++nt) {                                           \
            acc[ct][nt] = MFMA(XH_[ct], PH_[nt], acc[ct][nt]);                     \
            acc[ct][nt] = MFMA(XL_[ct], PH_[nt], acc[ct][nt]);                     \
            acc[ct][nt] = MFMA(XH_[ct], PL_[nt], acc[ct][nt]);                     \
        }                                                                          \
    }                                                                              \
} while (0)

    short8 xa_h[3], xa_l[3], pa_h[3], pa_l[3];
    short8 xb_h[3], xb_l[3], pb_h[3], pb_l[3];
    LOADF(xa_h, xa_l, pa_h, pa_l, 0);
    for (int k = 0; k < NN; k += 64) {
        LOADF(xb_h, xb_l, pb_h, pb_l, k + 32);
        COMP(xa_h, xa_l, pa_h, pa_l);
        int k2 = k + 64; if (k2 >= NN) k2 = 0;   // last prefetch wraps (unused)
        LOADF(xa_h, xa_l, pa_h, pa_l, k2);
        COMP(xb_h, xb_l, pb_h, pb_l);
    }
#undef LOADF
#undef COMP

    float* OTb = OT + (long)b * DD * NN;
    #pragma unroll
    for (int nt = 0; nt < 3; ++nt) {
        int rowl = wr * 48 + nt * 16 + l15;
        int row = n0 + rowl;
        float linv = 1.f / lsumG[(long)b * NN + row];
        float s1 = 0.f, s2 = 0.f;
        #pragma unroll
        for (int ct = 0; ct < 3; ++ct)
            #pragma unroll
            for (int e = 0; e < 4; ++e) {
                float vv = acc[ct][nt][e] * linv;
                acc[ct][nt][e] = vv;
                s1 += vv; s2 += vv * vv;
            }
        s1 += __shfl_xor(s1, 16); s1 += __shfl_xor(s1, 32);
        s2 += __shfl_xor(s2, 16); s2 += __shfl_xor(s2, 32);
        #pragma unroll
        for (int ct = 0; ct < 3; ++ct)
            #pragma unroll
            for (int e = 0; e < 4; ++e)
                OTb[(long)(cb + wc * 48 + ct * 16 + quad * 4 + e) * NN + row] =
                    acc[ct][nt][e];
        if (lane < 16) {
            atomicAdd(&stats[((long)b * NN + row) * 2 + 0], s1);
            atomicAdd(&stats[((long)b * NN + row) * 2 + 1], s2);
        }
    }
}

// ============ kernel B variant 2: pv_lds — R5 verified (124us control) =============
// X+P DMA'd to LDS double half-buf (2 x 24.5 KB); counted vmcnt(6); 2 bare
// barriers/phase; XCD-clustered grid. All staging via DMA -> no compiler-inserted
// vmcnt (only fast lgkmcnt for ds_read) -> pipeline preserved.
__global__ __launch_bounds__(256, 3) void pv_lds(
        const unsigned short* __restrict__ Ph, const unsigned short* __restrict__ Pl,
        const unsigned short* __restrict__ xTh, const unsigned short* __restrict__ xTl,
        const float* __restrict__ lsumG, float* __restrict__ OT,
        float* __restrict__ stats, int bofs) {
    __shared__ __align__(16) unsigned short SM[2][4][3072];  // [buf][arr][96r x 32k]
    const int t = threadIdx.x;
    const int w = t >> 6, lane = t & 63, quad = lane >> 4, l15 = lane & 15;
    const int wc = w & 1, wr = w >> 1;
    const int phys = blockIdx.x;
    const int gc = phys & 7;
    const int inner = phys >> 3;
    const int m = inner & 7;
    const int g = ((inner >> 3) << 3) + gc;
    const int cb = m * 96;
    const int n0 = (g % 24) * 96;
    const int bL = g / 24, b = bofs + bL;
    const unsigned short* xhb = xTh + (long)b * DD * NN;
    const unsigned short* xlb = xTl + (long)b * DD * NN;
    const unsigned short* phb = Ph + (long)bL * NN * NN;
    const unsigned short* plb = Pl + (long)bL * NN * NN;
    const unsigned short* srcArr = (w == 0) ? xhb : (w == 1) ? xlb
                                 : (w == 2) ? phb : plb;
    const int rbg = (w < 2) ? cb : n0;
    const int rl0 = lane >> 2, sl = lane & 3;

    f32x4 acc[3][3];
    #pragma unroll
    for (int ct = 0; ct < 3; ++ct)
        #pragma unroll
        for (int nt = 0; nt < 3; ++nt) acc[ct][nt] = 0.f;

#define STAGE(BUF_, K0_) do {                                                      \
    _Pragma("unroll")                                                              \
    for (int j = 0; j < 6; ++j) {                                                  \
        int rowL = j * 16 + rl0;                                                   \
        int koct = sl ^ ((rowL >> 1) & 3);                                         \
        __builtin_amdgcn_global_load_lds(                                          \
            (const __attribute__((address_space(1))) void*)                        \
                (srcArr + (long)(rbg + rowL) * NN + (K0_) + koct * 8),             \
            (__attribute__((address_space(3))) void*)&SM[BUF_][w][j * 512],        \
            16, 0, 0);                                                             \
    }                                                                              \
} while (0)

    STAGE(0, 0);
    for (int ph = 0; ph < NN / 32; ++ph) {
        const int buf = ph & 1;
        __builtin_amdgcn_s_barrier();             // all done reading buf^1
        {
            int kn = (ph + 1) * 32; if (kn >= NN) kn = 0;
            STAGE(buf ^ 1, kn);
        }
        asm volatile("s_waitcnt vmcnt(6)" ::: "memory");  // my phase-ph loads done
        __builtin_amdgcn_s_barrier();             // everyone's phase-ph loads done
        __builtin_amdgcn_sched_barrier(0);
        __builtin_amdgcn_s_setprio(1);
        {
            short8 pbh[3], pbl[3];
            #pragma unroll
            for (int nt = 0; nt < 3; ++nt) {
                int rl = wr * 48 + nt * 16 + l15;
                int so = rl * 32 + ((quad ^ ((rl >> 1) & 3)) * 8);
                pbh[nt] = *(const short8*)&SM[buf][2][so];
                pbl[nt] = *(const short8*)&SM[buf][3][so];
            }
            #pragma unroll
            for (int ct = 0; ct < 3; ++ct) {
                int cl = wc * 48 + ct * 16 + l15;
                int so = cl * 32 + ((quad ^ ((cl >> 1) & 3)) * 8);
                short8 axh = *(const short8*)&SM[buf][0][so];
                short8 axl = *(const short8*)&SM[buf][1][so];
                #pragma unroll
                for (int nt = 0; nt < 3; ++nt) {
                    acc[ct][nt] = MFMA(axh, pbh[nt], acc[ct][nt]);
                    acc[ct][nt] = MFMA(axl, pbh[nt], acc[ct][nt]);
                    acc[ct][nt] = MFMA(axh, pbl[nt], acc[ct][nt]);
                }
            }
        }
        __builtin_amdgcn_s_setprio(0);
    }
#undef STAGE

    float* OTb = OT + (long)b * DD * NN;
    #pragma unroll
    for (int nt = 0; nt < 3; ++nt) {
        int rowl = wr * 48 + nt * 16 + l15;
        int row = n0 + rowl;
        float linv = 1.f / lsumG[(long)b * NN + row];
        float s1 = 0.f, s2 = 0.f;
        #pragma unroll
        for (int ct = 0; ct < 3; ++ct)
            #pragma unroll
            for (int e = 0; e < 4; ++e) {
                float vv = acc[ct][nt][e] * linv;
                acc[ct][nt][e] = vv;
                s1 += vv; s2 += vv * vv;
            }
        s1 += __shfl_xor(s1, 16); s1 += __shfl_xor(s1, 32);
        s2 += __shfl_xor(s2, 16); s2 += __shfl_xor(s2, 32);
        #pragma unroll
        for (int ct = 0; ct < 3; ++ct)
            #pragma unroll
            for (int e = 0; e < 4; ++e)
                OTb[(long)(cb + wc * 48 + ct * 16 + quad * 4 + e) * NN + row] =
                    acc[ct][nt][e];
        if (lane < 16) {
            atomicAdd(&stats[((long)b * NN + row) * 2 + 0], s1);
            atomicAdd(&stats[((long)b * NN + row) * 2 + 1], s2);
        }
    }
}

// ===================== fallback fused attention (R3-v0, verified) ==================
#define ATTN_SETUP                                                                  \
    const int t = threadIdx.x;                                                      \
    const int w = t >> 6, lane = t & 63, quad = lane >> 4, l15 = lane & 15;         \
    const int bx = blockIdx.x;                                                      \
    const int combo = bx & 63, rt_idx = bx >> 6;                                    \
    const int b = combo & 7, g = combo >> 3;                                        \
    const int n0 = rt_idx * 96;                                                     \
    const int cb = g * 96;                                                          \
    const int sk = w & 1, sr = w >> 1;                                              \
    const int pbase = w * 1536;                                                     \
    if (t < 96) lsum[t] = 0.f;                                                      \
    const unsigned short* qhb = qhp + (long)b * NN * DM;                            \
    const unsigned short* qlb = qlp + (long)b * NN * DM;                            \
    const unsigned short* xhb = xTh + (long)b * DD * NN;                            \
    const unsigned short* xlb = xTl + (long)b * DD * NN;                            \
    short8 bh[3][2], bl[3][2];                                                      \
    _Pragma("unroll")                                                               \
    for (int rt = 0; rt < 3; ++rt) {                                                \
        _Pragma("unroll")                                                           \
        for (int kc = 0; kc < 2; ++kc) {                                            \
            long o = (long)(n0 + sr * 48 + rt * 16 + l15) * DM + kc * 32 + quad * 8;\
            bh[rt][kc] = *(const short8*)(qhb + o);                                 \
            bl[rt][kc] = *(const short8*)(qlb + o);                                 \
        }                                                                           \
    }                                                                               \
    float lp[3] = {0.f, 0.f, 0.f};                                                  \
    f32x4 acc[6][3];                                                                \
    _Pragma("unroll")                                                               \
    for (int ct = 0; ct < 6; ++ct) {                                                \
        _Pragma("unroll")                                                           \
        for (int nt = 0; nt < 3; ++nt) acc[ct][nt] = 0.f;                           \
    }

#define DMA_X(DH_, DL_, KB_) do {                                                   \
    _Pragma("unroll")                                                               \
    for (int j = 0; j < 6; ++j) {                                                   \
        int cg = w * 6 + j;                                                         \
        int cm = cg - (cg >= 12 ? 12 : 0);                                          \
        unsigned short* dstb = (cg < 12 ? (DH_) : (DL_)) + cm * 512;                \
        const unsigned short* srcb = (cg < 12 ? xhb : xlb);                         \
        int col = cm * 8 + (lane >> 3);                                             \
        int key = ((lane & 7) ^ (col & 7)) * 8;                                     \
        __builtin_amdgcn_global_load_lds(                                           \
            (const __attribute__((address_space(1))) void*)                         \
                (srcb + (long)(cb + col) * NN + (KB_) + key),                       \
            (__attribute__((address_space(3))) void*)dstb, 16, 0, 0);               \
    }                                                                               \
} while (0)

#define QPF(QN_, KQ_) do {                                                          \
    _Pragma("unroll")                                                               \
    for (int kt = 0; kt < 2; ++kt) {                                                \
        long o = (long)((KQ_) + sk * 32 + kt * 16 + l15) * DM + quad * 8;           \
        QN_[kt * 4 + 0] = *(const short8*)(qhb + o);                                \
        QN_[kt * 4 + 1] = *(const short8*)(qhb + o + 32);                           \
        QN_[kt * 4 + 2] = *(const short8*)(qlb + o);                                \
        QN_[kt * 4 + 3] = *(const short8*)(qlb + o + 32);                           \
    }                                                                               \
} while (0)

#define S_KT(QH0_, QH1_, QL0_, QL1_, KT_) do {                                      \
    _Pragma("unroll")                                                               \
    for (int rt = 0; rt < 3; ++rt) {                                                \
        f32x4 s = 0.f;                                                              \
        s = MFMA(QH0_, bh[rt][0], s);                                               \
        s = MFMA(QH1_, bh[rt][1], s);                                               \
        s = MFMA(QL0_, bh[rt][0], s);                                               \
        s = MFMA(QL1_, bh[rt][1], s);                                               \
        s = MFMA(QH0_, bl[rt][0], s);                                               \
        s = MFMA(QH1_, bl[rt][1], s);                                               \
        float p0 = __expf(s[0] * 0.125f);                                           \
        float p1 = __expf(s[1] * 0.125f);                                           \
        float p2 = __expf(s[2] * 0.125f);                                           \
        float p3 = __expf(s[3] * 0.125f);                                           \
        lp[rt] += (p0 + p1) + (p2 + p3);                                            \
        unsigned u0 = __float_as_uint(p0), u1 = __float_as_uint(p1);                \
        unsigned u2 = __float_as_uint(p2), u3 = __float_as_uint(p3);                \
        uint2v dh = { (u0 >> 16) | (u1 & 0xFFFF0000u),                              \
                      (u2 >> 16) | (u3 & 0xFFFF0000u) };                            \
        float r0 = p0 - __uint_as_float(u0 & 0xFFFF0000u);                          \
        float r1 = p1 - __uint_as_float(u1 & 0xFFFF0000u);                          \
        float r2 = p2 - __uint_as_float(u2 & 0xFFFF0000u);                          \
        float r3 = p3 - __uint_as_float(u3 & 0xFFFF0000u);                          \
        unsigned v0 = __float_as_uint(r0), v1 = __float_as_uint(r1);                \
        unsigned v2 = __float_as_uint(r2), v3 = __float_as_uint(r3);                \
        uint2v dl = { (v0 >> 16) | (v1 & 0xFFFF0000u),                              \
                      (v2 >> 16) | (v3 & 0xFFFF0000u) };                            \
        int rr_ = rt * 16 + l15;                                                    \
        int ff_ = (((rr_ & 7) ^ (rr_ >> 3)) & 7) << 2;                              \
        int ix_ = pbase + rr_ * 32 + (((KT_) * 16 + quad * 4) ^ ff_);               \
        *(uint2v*)&PHs[ix_] = dh;                                                   \
        *(uint2v*)&PLs[ix_] = dl;                                                   \
    }                                                                               \
} while (0)

#define PV_PHASE(XH_, XL_) do {                                                     \
    short8 pbh[3], pbl[3];                                                          \
    _Pragma("unroll")                                                               \
    for (int nt = 0; nt < 3; ++nt) {                                                \
        int r_ = nt * 16 + l15;                                                     \
        int ff_ = (((r_ & 7) ^ (r_ >> 3)) & 7) << 2;                                \
        int i0 = pbase + r_ * 32 + ((quad * 8) ^ ff_);                              \
        int i1 = pbase + r_ * 32 + ((quad * 8 + 4) ^ ff_);                          \
        short4v h0 = *(const short4v*)&PHs[i0];                                     \
        short4v h1 = *(const short4v*)&PHs[i1];                                     \
        short4v l0 = *(const short4v*)&PLs[i0];                                     \
        short4v l1 = *(const short4v*)&PLs[i1];                                     \
        pbh[nt] = __builtin_shufflevector(h0, h1, 0, 1, 2, 3, 4, 5, 6, 7);          \
        pbl[nt] = __builtin_shufflevector(l0, l1, 0, 1, 2, 3, 4, 5, 6, 7);          \
    }                                                                               \
    _Pragma("unroll")                                                               \
    for (int ct = 0; ct < 6; ++ct) {                                                \
        int colx = ct * 16 + l15;                                                   \
        int xk = (sk * 32 + quad * 8) ^ ((colx & 7) << 3);                          \
        short8 axh = *(const short8*)&(XH_)[colx * 64 + xk];                        \
        short8 axl = *(const short8*)&(XL_)[colx * 64 + xk];                        \
        _Pragma("unroll")                                                           \
        for (int nt = 0; nt < 3; ++nt) {                                            \
            acc[ct][nt] = MFMA(axh, pbh[nt], acc[ct][nt]);                          \
            acc[ct][nt] = MFMA(axl, pbh[nt], acc[ct][nt]);                          \
            acc[ct][nt] = MFMA(axh, pbl[nt], acc[ct][nt]);                          \
        }                                                                           \
    }                                                                               \
} while (0)

#define ATTN_EPILOGUE do {                                                          \
    _Pragma("unroll")                                                               \
    for (int rt = 0; rt < 3; ++rt) {                                                \
        float v = lp[rt];                                                           \
        v += __shfl_xor(v, 16); v += __shfl_xor(v, 32);                             \
        if (lane < 16) atomicAdd(&lsum[sr * 48 + rt * 16 + l15], v);                \
    }                                                                               \
    float* M = (float*)SMEM;                                                        \
    __syncthreads();                                                                \
    if (sk == 1) {                                                                  \
        float* Mw = M + sr * (48 * 100);                                            \
        _Pragma("unroll")                                                           \
        for (int nt = 0; nt < 3; ++nt) {                                            \
            _Pragma("unroll")                                                       \
            for (int ct = 0; ct < 6; ++ct)                                          \
                *(f32x4*)&Mw[(nt * 16 + l15) * 100 + ct * 16 + quad * 4] = acc[ct][nt]; \
        }                                                                           \
    }                                                                               \
    __syncthreads();                                                                \
    if (sk == 0) {                                                                  \
        const float* Mr = M + sr * (48 * 100);                                      \
        float* OTb = OT + (long)b * DD * NN;                                        \
        _Pragma("unroll")                                                           \
        for (int nt = 0; nt < 3; ++nt) {                                            \
            int rowl = sr * 48 + nt * 16 + l15;                                     \
            int row = n0 + rowl;                                                    \
            float linv = 1.f / lsum[rowl];                                          \
            float s1 = 0.f, s2 = 0.f;                                               \
            _Pragma("unroll")                                                       \
            for (int ct = 0; ct < 6; ++ct) {                                        \
                f32x4 pq = *(const f32x4*)&Mr[(nt * 16 + l15) * 100 + ct * 16 + quad * 4]; \
                _Pragma("unroll")                                                   \
                for (int e = 0; e < 4; ++e) {                                       \
                    float vv = (acc[ct][nt][e] + pq[e]) * linv;                     \
                    acc[ct][nt][e] = vv;                                            \
                    s1 += vv; s2 += vv * vv;                                        \
                }                                                                   \
            }                                                                       \
            s1 += __shfl_xor(s1, 16); s1 += __shfl_xor(s1, 32);                     \
            s2 += __shfl_xor(s2, 16); s2 += __shfl_xor(s2, 32);                     \
            _Pragma("unroll")                                                       \
            for (int ct = 0; ct < 6; ++ct) {                                        \
                _Pragma("unroll")                                                   \
                for (int e = 0; e < 4; ++e)                                         \
                    OTb[(long)(cb + ct * 16 + quad * 4 + e) * NN + row] = acc[ct][nt][e]; \
            }                                                                       \
            if (lane < 16) {                                                        \
                atomicAdd(&stats[((long)b * NN + row) * 2 + 0], s1);                \
                atomicAdd(&stats[((long)b * NN + row) * 2 + 1], s2);                \
            }                                                                       \
        }                                                                           \
    }                                                                               \
} while (0)

__global__ __launch_bounds__(256, 2) void attn_v0(
        const unsigned short* __restrict__ qhp, const unsigned short* __restrict__ qlp,
        const unsigned short* __restrict__ xTh, const unsigned short* __restrict__ xTl,
        float* __restrict__ OT, float* __restrict__ stats) {
    __shared__ __align__(16) unsigned char SMEM[49536];
    unsigned short* XHs = (unsigned short*)SMEM;
    unsigned short* XLs = XHs + 6144;
    unsigned short* PHs = XHs + 12288;
    unsigned short* PLs = XHs + 18432;
    float* lsum = (float*)(SMEM + 49152);
    ATTN_SETUP;
    short8 qA[8], qB[8];
    QPF(qA, 0);
    for (int kp = 0; kp < NN; kp += 128) {
        __syncthreads();
        DMA_X(XHs, XLs, kp);
        { int kq = kp + 64; QPF(qB, kq); }
        S_KT(qA[0], qA[1], qA[2], qA[3], 0);
        S_KT(qA[4], qA[5], qA[6], qA[7], 1);
        __syncthreads();
        __builtin_amdgcn_s_setprio(1);
        PV_PHASE(XHs, XLs);
        __builtin_amdgcn_s_setprio(0);
        __syncthreads();
        DMA_X(XHs, XLs, kp + 64);
        { int kq = kp + 128; if (kq >= NN) kq = 0; QPF(qA, kq); }
        S_KT(qB[0], qB[1], qB[2], qB[3], 0);
        S_KT(qB[4], qB[5], qB[6], qB[7], 1);
        __syncthreads();
        __builtin_amdgcn_s_setprio(1);
        PV_PHASE(XHs, XLs);
        __builtin_amdgcn_s_setprio(0);
    }
    ATTN_EPILOGUE;
}

// ---------- LN apply (mid layers): O^T fp32 -> split-bf16 xT ------------------------
__global__ __launch_bounds__(256) void lncvt_mid_kernel(
        const float* __restrict__ OT, const float* __restrict__ stats,
        const float* __restrict__ gamma, const float* __restrict__ beta,
        unsigned short* __restrict__ xTh, unsigned short* __restrict__ xTl) {
    int t = threadIdx.x;
    int n = blockIdx.x * 64 + (t & 63);
    int b = blockIdx.z;
    int c0 = blockIdx.y * 192 + (t >> 6);
    float s1 = stats[((long)b * NN + n) * 2 + 0];
    float s2 = stats[((long)b * NN + n) * 2 + 1];
    float mu = s1 * (1.f / 768.f);
    float rs = rsqrtf(s2 * (1.f / 768.f) - mu * mu + EPSF);
    const float* OTb = OT + (long)b * DD * NN;
    #pragma unroll 4
    for (int i = 0; i < 48; ++i) {
        int c = c0 + i * 4;
        float o = OTb[(long)c * NN + n];
        float y = (o - mu) * rs * gamma[c] + beta[c];
        unsigned short h = f2b(y);
        long idx = ((long)b * DD + c) * NN + n;
        xTh[idx] = h;
        xTl[idx] = f2b(y - b2f(h));
    }
}

// ---------- LN apply (final): O^T fp32 -> out fp32 [B][N][D] via LDS transpose ------
__global__ __launch_bounds__(256) void lncvt_final_kernel(
        const float* __restrict__ OT, const float* __restrict__ stats,
        const float* __restrict__ gamma, const float* __restrict__ beta,
        float* __restrict__ out) {
    __shared__ float T[64][65];
    int t = threadIdx.x;
    int nl = t & 63, cw = t >> 6;
    int b = blockIdx.y, n0 = blockIdx.x * 64;
    int n = n0 + nl;
    float s1 = stats[((long)b * NN + n) * 2 + 0];
    float s2 = stats[((long)b * NN + n) * 2 + 1];
    float mu = s1 * (1.f / 768.f);
    float rs = rsqrtf(s2 * (1.f / 768.f) - mu * mu + EPSF);
    const float* OTb = OT + (long)b * DD * NN;
    float* ob = out + (long)b * NN * DD;
    int row_l = t >> 2, seg = t & 3;
    for (int ct = 0; ct < 12; ++ct) {
        #pragma unroll
        for (int i = 0; i < 16; ++i) {
            int cl = cw + i * 4;
            int c = ct * 64 + cl;
            float o = OTb[(long)c * NN + n];
            T[nl][cl] = (o - mu) * rs * gamma[c] + beta[c];
        }
        __syncthreads();
        #pragma unroll
        for (int i = 0; i < 4; ++i) {
            int cl = seg * 16 + i * 4;
            float4 v = *(const float4*)&T[row_l][cl];
            *(float4*)&ob[(long)(n0 + row_l) * DD + ct * 64 + cl] = v;
        }
        __syncthreads();
    }
}

extern "C" void kernel_launch(void* const* d_in, const int* in_sizes, int n_in,
                              void* d_out, int out_size, void* d_ws, size_t ws_size,
                              hipStream_t stream) {
    (void)in_sizes; (void)n_in; (void)out_size;
    const float* x     = (const float*)d_in[0];
    const float* Wq    = (const float*)d_in[1];
    const float* bq    = (const float*)d_in[2];
    const float* gamma = (const float*)d_in[3];
    const float* beta  = (const float*)d_in[4];
    float* out = (float*)d_out;

    char* p = (char*)d_ws;
    const size_t szXT = (size_t)BB * DD * NN * 2;          // 28.3 MB
    unsigned short* xTh = (unsigned short*)p; p += szXT;
    unsigned short* xTl = (unsigned short*)p; p += szXT;
    float* OT           = (float*)p;          p += (size_t)BB * DD * NN * 4;   // 56.6 MB
    unsigned short* qh  = (unsigned short*)p; p += (size_t)BB * NN * DM * 2;
    unsigned short* ql  = (unsigned short*)p; p += (size_t)BB * NN * DM * 2;
    float* stats        = (float*)p;          p += (size_t)BB * NN * 2 * 4;
    float* lsumG        = (float*)p;          p += (size_t)BB * NN * 4;   // after stats!
    unsigned short* Wth = (unsigned short*)p; p += (size_t)DM * DD * 2;
    unsigned short* Wtl = (unsigned short*)p; p += (size_t)DM * DD * 2;

    // per-batch P (hi+lo) from the remaining workspace; choose group size gb
    size_t used = (size_t)(p - (char*)d_ws);
    const size_t perB = (size_t)NN * NN * 2 * 2;           // 21.2 MB per batch
    int gb = 0;
    if      (ws_size >= used + 8 * perB) gb = 8;
    else if (ws_size >= used + 4 * perB) gb = 4;
    else if (ws_size >= used + 2 * perB) gb = 2;
    else if (ws_size >= used + 1 * perB) gb = 1;
    unsigned short* Ph = (unsigned short*)p;
    unsigned short* Pl = Ph + (size_t)(gb > 0 ? gb : 1) * NN * NN;

    cvt_kernel<<<dim3(NN / 64, DD / 64, BB), 256, 0, stream>>>(x, xTh, xTl);
    wqcvt_kernel<<<dim3(DD * DM / 256), 256, 0, stream>>>(Wq, Wth, Wtl);

    for (int layer = 0; layer < 3; ++layer) {
        proj_kernel<<<dim3(NN / 64, BB), 256, 0, stream>>>(Wth, Wtl, xTh, xTl, bq, qh, ql);
        zstats_kernel<<<dim3(BB * NN * 3 / 256), 256, 0, stream>>>(stats); // stats+lsumG
        if (gb > 0) {
            for (int g0 = 0; g0 < BB; g0 += gb) {
                qk_kernel<<<dim3(NN / 96, 12, gb), 256, 0, stream>>>(
                    qh, ql, Ph, Pl, lsumG, g0);
                if (layer < 2)
                    pv_stream<<<dim3(8 * (NN / 96) * gb), 256, 0, stream>>>(
                        Ph, Pl, xTh, xTl, lsumG, OT, stats, g0);
                else
                    pv_lds<<<dim3(8 * (NN / 96) * gb), 256, 0, stream>>>(
                        Ph, Pl, xTh, xTl, lsumG, OT, stats, g0);
            }
        } else {
            attn_v0<<<dim3(24 * 64), 256, 0, stream>>>(qh, ql, xTh, xTl, OT, stats);
        }
        if (layer < 2)
            lncvt_mid_kernel<<<dim3(NN / 64, 4, BB), 256, 0, stream>>>(OT, stats, gamma, beta, xTh, xTl);
        else
            lncvt_final_kernel<<<dim3(NN / 64, BB), 256, 0, stream>>>(OT, stats, gamma, beta, out);
    }
}

// Round 9
// 1211.268 us; speedup vs baseline: 1.6351x; 1.6351x over previous
//
#include <hip/hip_runtime.h>
#include <math.h>

#define BB 8
#define NN 2304
#define DD 768
#define DM 64
#define EPSF 1e-5f

typedef __attribute__((ext_vector_type(8))) short short8;   // 8 x bf16 bits (16 B)
typedef __attribute__((ext_vector_type(4))) short short4v;  // 4 x bf16 bits (8 B)
typedef __attribute__((ext_vector_type(4))) float f32x4;
typedef __attribute__((ext_vector_type(2))) unsigned int uint2v;

static __device__ __forceinline__ unsigned short f2b(float f) {
    unsigned u = __float_as_uint(f);
    unsigned r = u + 0x7FFFu + ((u >> 16) & 1u);
    return (unsigned short)(r >> 16);
}
static __device__ __forceinline__ float b2f(unsigned short h) {
    return __uint_as_float(((unsigned)h) << 16);
}
#define MFMA(a, b, c) __builtin_amdgcn_mfma_f32_16x16x32_bf16((a), (b), (c), 0, 0, 0)

// ---------- layer-0: fp32 x [B][N][D] -> split-bf16 transposed xT_hi/lo [B][D][N] ----
__global__ __launch_bounds__(256) void cvt_kernel(const float* __restrict__ xf,
                                                  unsigned short* __restrict__ xTh,
                                                  unsigned short* __restrict__ xTl) {
    __shared__ __align__(16) unsigned short Th[64][72];
    __shared__ __align__(16) unsigned short Tl[64][72];
    int t = threadIdx.x;
    int b = blockIdx.z;
    int n0 = blockIdx.x * 64, c0 = blockIdx.y * 64;
    int rr = t >> 4, cc = (t & 15) * 4;
    #pragma unroll
    for (int i = 0; i < 4; ++i) {
        int r = rr + i * 16;
        long idx = ((long)b * NN + n0 + r) * DD + c0 + cc;
        float4 v = *(const float4*)&xf[idx];
        unsigned short h0 = f2b(v.x), h1 = f2b(v.y), h2 = f2b(v.z), h3 = f2b(v.w);
        Th[cc + 0][r] = h0; Th[cc + 1][r] = h1; Th[cc + 2][r] = h2; Th[cc + 3][r] = h3;
        Tl[cc + 0][r] = f2b(v.x - b2f(h0));
        Tl[cc + 1][r] = f2b(v.y - b2f(h1));
        Tl[cc + 2][r] = f2b(v.z - b2f(h2));
        Tl[cc + 3][r] = f2b(v.w - b2f(h3));
    }
    __syncthreads();
    #pragma unroll
    for (int i = 0; i < 4; ++i) {
        int c = rr + i * 16;
        long idx = ((long)b * DD + c0 + c) * NN + n0 + cc;
        *(ushort4*)&xTh[idx] = *(const ushort4*)&Th[c][cc];
        *(ushort4*)&xTl[idx] = *(const ushort4*)&Tl[c][cc];
    }
}

// ---------- Wq fp32 [768][64] -> transposed split bf16 Wt_hi/lo [64][768] ----------
__global__ __launch_bounds__(256) void wqcvt_kernel(const float* __restrict__ Wq,
                                                    unsigned short* __restrict__ Wth,
                                                    unsigned short* __restrict__ Wtl) {
    int t = blockIdx.x * 256 + threadIdx.x;   // t < 768*64
    int d = t >> 6, m = t & 63;
    float v = Wq[t];
    unsigned short h = f2b(v);
    Wth[m * DD + d] = h;
    Wtl[m * DD + d] = f2b(v - b2f(h));
}

// zeroes stats (2 floats/row) + lsumG (1 float/row), contiguous: 3*BB*NN floats
__global__ __launch_bounds__(256) void zstats_kernel(float* __restrict__ stats) {
    stats[blockIdx.x * 256 + threadIdx.x] = 0.f;
}

// ---------- MFMA q-projection ------------------------------------------------------
__global__ __launch_bounds__(256) void proj_kernel(
        const unsigned short* __restrict__ Wth, const unsigned short* __restrict__ Wtl,
        const unsigned short* __restrict__ xTh, const unsigned short* __restrict__ xTl,
        const float* __restrict__ bq,
        unsigned short* __restrict__ qh, unsigned short* __restrict__ ql) {
    int t = threadIdx.x;
    int w = t >> 6, lane = t & 63, quad = lane >> 4, l15 = lane & 15;
    int n0 = blockIdx.x * 64, b = blockIdx.y;
    const unsigned short* xhb = xTh + (long)b * DD * NN;
    const unsigned short* xlb = xTl + (long)b * DD * NN;

    f32x4 accQ[4];
    #pragma unroll
    for (int nt = 0; nt < 4; ++nt) accQ[nt] = 0.f;

    for (int d0 = 0; d0 < DD; d0 += 32) {
        short8 ah = *(const short8*)&Wth[(w * 16 + l15) * DD + d0 + quad * 8];
        short8 al = *(const short8*)&Wtl[(w * 16 + l15) * DD + d0 + quad * 8];
        #pragma unroll
        for (int nt = 0; nt < 4; ++nt) {
            int row = n0 + nt * 16 + l15;
            short8 bh, bl;
            #pragma unroll
            for (int j = 0; j < 8; ++j) {
                long o = (long)(d0 + quad * 8 + j) * NN + row;
                bh[j] = (short)xhb[o];
                bl[j] = (short)xlb[o];
            }
            accQ[nt] = MFMA(ah, bh, accQ[nt]);
            accQ[nt] = MFMA(al, bh, accQ[nt]);
            accQ[nt] = MFMA(ah, bl, accQ[nt]);
        }
    }
    #pragma unroll
    for (int nt = 0; nt < 4; ++nt) {
        int row = n0 + nt * 16 + l15;
        #pragma unroll
        for (int e = 0; e < 4; ++e) {
            int qm = w * 16 + quad * 4 + e;
            float v = accQ[nt][e] + bq[qm];
            unsigned short h = f2b(v);
            long o = ((long)b * NN + row) * DM + qm;
            qh[o] = h;
            ql[o] = f2b(v - b2f(h));
        }
    }
}

// ============ kernel A: S = q.q^T, exp, split-bf16 pack -> global P ================
// P computed once per (b,row). Coalesced stores via wave-private swizzled LDS
// staging. grid (24, 12, gb): 192 keys/block (3 iters) for occupancy; 4 waves.
__global__ __launch_bounds__(256) void qk_kernel(
        const unsigned short* __restrict__ qhp, const unsigned short* __restrict__ qlp,
        unsigned short* __restrict__ Ph, unsigned short* __restrict__ Pl,
        float* __restrict__ lsumG, int bofs) {
    __shared__ __align__(16) unsigned short PHs[4 * 1536];  // [wave][48r x 32k]
    __shared__ __align__(16) unsigned short PLs[4 * 1536];
    const int t = threadIdx.x;
    const int w = t >> 6, lane = t & 63, quad = lane >> 4, l15 = lane & 15;
    const int sk = w & 1, sr = w >> 1;
    const int pbase = w * 1536;
    const int n0 = blockIdx.x * 96;
    const int k00 = blockIdx.y * 192;
    const int bL = blockIdx.z, b = bofs + bL;
    const unsigned short* qhb = qhp + (long)b * NN * DM;
    const unsigned short* qlb = qlp + (long)b * NN * DM;

    short8 bh[3][2], bl[3][2];
    #pragma unroll
    for (int rt = 0; rt < 3; ++rt)
        #pragma unroll
        for (int kc = 0; kc < 2; ++kc) {
            long o = (long)(n0 + sr * 48 + rt * 16 + l15) * DM + kc * 32 + quad * 8;
            bh[rt][kc] = *(const short8*)(qhb + o);
            bl[rt][kc] = *(const short8*)(qlb + o);
        }
    float lp[3] = {0.f, 0.f, 0.f};

    for (int k0 = k00; k0 < k00 + 192; k0 += 64) {
        #pragma unroll
        for (int kt = 0; kt < 2; ++kt) {
            long ao = (long)(k0 + sk * 32 + kt * 16 + l15) * DM + quad * 8;
            short8 qh0 = *(const short8*)(qhb + ao);
            short8 qh1 = *(const short8*)(qhb + ao + 32);
            short8 ql0 = *(const short8*)(qlb + ao);
            short8 ql1 = *(const short8*)(qlb + ao + 32);
            #pragma unroll
            for (int rt = 0; rt < 3; ++rt) {
                f32x4 s = 0.f;
                s = MFMA(qh0, bh[rt][0], s);
                s = MFMA(qh1, bh[rt][1], s);
                s = MFMA(ql0, bh[rt][0], s);
                s = MFMA(ql1, bh[rt][1], s);
                s = MFMA(qh0, bl[rt][0], s);
                s = MFMA(qh1, bl[rt][1], s);
                float p0 = __expf(s[0] * 0.125f);
                float p1 = __expf(s[1] * 0.125f);
                float p2 = __expf(s[2] * 0.125f);
                float p3 = __expf(s[3] * 0.125f);
                lp[rt] += (p0 + p1) + (p2 + p3);
                unsigned u0 = __float_as_uint(p0), u1 = __float_as_uint(p1);
                unsigned u2 = __float_as_uint(p2), u3 = __float_as_uint(p3);
                uint2v dh = { (u0 >> 16) | (u1 & 0xFFFF0000u),
                              (u2 >> 16) | (u3 & 0xFFFF0000u) };
                float r0 = p0 - __uint_as_float(u0 & 0xFFFF0000u);
                float r1 = p1 - __uint_as_float(u1 & 0xFFFF0000u);
                float r2 = p2 - __uint_as_float(u2 & 0xFFFF0000u);
                float r3 = p3 - __uint_as_float(u3 & 0xFFFF0000u);
                unsigned v0 = __float_as_uint(r0), v1 = __float_as_uint(r1);
                unsigned v2 = __float_as_uint(r2), v3 = __float_as_uint(r3);
                uint2v dl = { (v0 >> 16) | (v1 & 0xFFFF0000u),
                              (v2 >> 16) | (v3 & 0xFFFF0000u) };
                int rr = rt * 16 + l15;
                int ff = (((rr & 7) ^ (rr >> 3)) & 7) << 2;
                int ix = pbase + rr * 32 + ((kt * 16 + quad * 4) ^ ff);
                *(uint2v*)&PHs[ix] = dh;
                *(uint2v*)&PLs[ix] = dl;
            }
        }
        // readback (undo swizzle) + coalesced 16B stores: 4 lanes = 64B per row
        #pragma unroll
        for (int r = 0; r < 3; ++r) {
            int c = r * 64 + lane;          // 192 chunks = 48 rows x 4 segs
            int rr = c >> 2, s = c & 3;
            int ff = (((rr & 7) ^ (rr >> 3)) & 7) << 2;
            int i0 = pbase + rr * 32 + ((s * 8) ^ ff);
            int i1 = pbase + rr * 32 + ((s * 8 + 4) ^ ff);
            short4v h0 = *(const short4v*)&PHs[i0];
            short4v h1 = *(const short4v*)&PHs[i1];
            short4v l0 = *(const short4v*)&PLs[i0];
            short4v l1 = *(const short4v*)&PLs[i1];
            short8 hh = __builtin_shufflevector(h0, h1, 0, 1, 2, 3, 4, 5, 6, 7);
            short8 ll = __builtin_shufflevector(l0, l1, 0, 1, 2, 3, 4, 5, 6, 7);
            long po = ((long)bL * NN + n0 + sr * 48 + rr) * NN + k0 + sk * 32 + s * 8;
            *(short8*)&Ph[po] = hh;
            *(short8*)&Pl[po] = ll;
        }
    }
    #pragma unroll
    for (int rt = 0; rt < 3; ++rt) {
        float v = lp[rt];
        v += __shfl_xor(v, 16); v += __shfl_xor(v, 32);
        if (lane < 16)
            atomicAdd(&lsumG[(long)b * NN + n0 + sr * 48 + rt * 16 + l15], v);
    }
}

// ============ kernel B variant 1: pv_lds128 — 128x128 tile, 64x64 wave tile ========
// Same verified skeleton as pv_lds (DMA all 4 arrays, bare barriers, counted vmcnt,
// setprio), but wave register-tile 64x64: 16 LDS b128 reads feed 48 MFMA (ratio 3.0
// vs 2.25) -> MFMA-dominant per-CU cycle budget. LDS 64 KB, 2 blocks/CU.
// Grid 6m x 18n x gb, XCD-clustered (6 members/group; chunk divides when nwg%8==0).
__global__ __launch_bounds__(256, 2) void pv_lds128(
        const unsigned short* __restrict__ Ph, const unsigned short* __restrict__ Pl,
        const unsigned short* __restrict__ xTh, const unsigned short* __restrict__ xTl,
        const float* __restrict__ lsumG, float* __restrict__ OT,
        float* __restrict__ stats, int bofs) {
    __shared__ __align__(16) unsigned short SM[2][4][4096];  // [buf][arr][128 x 32k]
    const int t = threadIdx.x;
    const int w = t >> 6, lane = t & 63, quad = lane >> 4, l15 = lane & 15;
    const int wc = w & 1, wr = w >> 1;
    const int B = blockIdx.x;
    const int nwg = gridDim.x;
    int logical;
    if ((nwg & 7) == 0) { int chunk = nwg >> 3; logical = (B & 7) * chunk + (B >> 3); }
    else logical = B;
    const int m = logical % (DD / 128);
    const int rest = logical / (DD / 128);
    const int n0i = rest % (NN / 128);
    const int bL = rest / (NN / 128), b = bofs + bL;
    const int cb = m * 128;
    const int n0 = n0i * 128;
    const unsigned short* xhb = xTh + (long)b * DD * NN;
    const unsigned short* xlb = xTl + (long)b * DD * NN;
    const unsigned short* phb = Ph + (long)bL * NN * NN;
    const unsigned short* plb = Pl + (long)bL * NN * NN;
    const unsigned short* srcArr = (w == 0) ? xhb : (w == 1) ? xlb
                                 : (w == 2) ? phb : plb;
    const int rbg = (w < 2) ? cb : n0;
    const int rl0 = lane >> 2, sl = lane & 3;

    f32x4 acc[4][4];
    #pragma unroll
    for (int ct = 0; ct < 4; ++ct)
        #pragma unroll
        for (int nt = 0; nt < 4; ++nt) acc[ct][nt] = 0.f;

    // store key-octet swizzled by ((row>>1)&3); read with matching XOR (R5-verified)
#define STAGE(BUF_, K0_) do {                                                      \
    _Pragma("unroll")                                                              \
    for (int j = 0; j < 8; ++j) {                                                  \
        int rowL = j * 16 + rl0;                                                   \
        int koct = sl ^ ((rowL >> 1) & 3);                                         \
        __builtin_amdgcn_global_load_lds(                                          \
            (const __attribute__((address_space(1))) void*)                        \
                (srcArr + (long)(rbg + rowL) * NN + (K0_) + koct * 8),             \
            (__attribute__((address_space(3))) void*)&SM[BUF_][w][j * 512],        \
            16, 0, 0);                                                             \
    }                                                                              \
} while (0)

    STAGE(0, 0);
    for (int ph = 0; ph < NN / 32; ++ph) {
        const int buf = ph & 1;
        __builtin_amdgcn_s_barrier();             // all done reading buf^1
        {
            int kn = (ph + 1) * 32; if (kn >= NN) kn = 0;
            STAGE(buf ^ 1, kn);
        }
        asm volatile("s_waitcnt vmcnt(8)" ::: "memory");  // my phase-ph loads done
        __builtin_amdgcn_s_barrier();             // everyone's phase-ph loads done
        __builtin_amdgcn_sched_barrier(0);
        __builtin_amdgcn_s_setprio(1);
        {
            short8 pbh[4], pbl[4];
            #pragma unroll
            for (int nt = 0; nt < 4; ++nt) {
                int rl = wr * 64 + nt * 16 + l15;
                int so = rl * 32 + ((quad ^ ((rl >> 1) & 3)) * 8);
                pbh[nt] = *(const short8*)&SM[buf][2][so];
                pbl[nt] = *(const short8*)&SM[buf][3][so];
            }
            #pragma unroll
            for (int ct = 0; ct < 4; ++ct) {
                int cl = wc * 64 + ct * 16 + l15;
                int so = cl * 32 + ((quad ^ ((cl >> 1) & 3)) * 8);
                short8 axh = *(const short8*)&SM[buf][0][so];
                short8 axl = *(const short8*)&SM[buf][1][so];
                #pragma unroll
                for (int nt = 0; nt < 4; ++nt) {
                    acc[ct][nt] = MFMA(axh, pbh[nt], acc[ct][nt]);
                    acc[ct][nt] = MFMA(axl, pbh[nt], acc[ct][nt]);
                    acc[ct][nt] = MFMA(axh, pbl[nt], acc[ct][nt]);
                }
            }
        }
        __builtin_amdgcn_s_setprio(0);
    }
#undef STAGE

    float* OTb = OT + (long)b * DD * NN;
    #pragma unroll
    for (int nt = 0; nt < 4; ++nt) {
        int rowl = wr * 64 + nt * 16 + l15;
        int row = n0 + rowl;
        float linv = 1.f / lsumG[(long)b * NN + row];
        float s1 = 0.f, s2 = 0.f;
        #pragma unroll
        for (int ct = 0; ct < 4; ++ct)
            #pragma unroll
            for (int e = 0; e < 4; ++e) {
                float vv = acc[ct][nt][e] * linv;
                acc[ct][nt][e] = vv;
                s1 += vv; s2 += vv * vv;
            }
        s1 += __shfl_xor(s1, 16); s1 += __shfl_xor(s1, 32);
        s2 += __shfl_xor(s2, 16); s2 += __shfl_xor(s2, 32);
        #pragma unroll
        for (int ct = 0; ct < 4; ++ct)
            #pragma unroll
            for (int e = 0; e < 4; ++e)
                OTb[(long)(cb + wc * 64 + ct * 16 + quad * 4 + e) * NN + row] =
                    acc[ct][nt][e];
        if (lane < 16) {
            atomicAdd(&stats[((long)b * NN + row) * 2 + 0], s1);
            atomicAdd(&stats[((long)b * NN + row) * 2 + 1], s2);
        }
    }
}

// ============ kernel B variant 2: pv_lds — R5 verified (124us control) =============
__global__ __launch_bounds__(256, 3) void pv_lds(
        const unsigned short* __restrict__ Ph, const unsigned short* __restrict__ Pl,
        const unsigned short* __restrict__ xTh, const unsigned short* __restrict__ xTl,
        const float* __restrict__ lsumG, float* __restrict__ OT,
        float* __restrict__ stats, int bofs) {
    __shared__ __align__(16) unsigned short SM[2][4][3072];  // [buf][arr][96r x 32k]
    const int t = threadIdx.x;
    const int w = t >> 6, lane = t & 63, quad = lane >> 4, l15 = lane & 15;
    const int wc = w & 1, wr = w >> 1;
    const int phys = blockIdx.x;
    const int gc = phys & 7;
    const int inner = phys >> 3;
    const int m = inner & 7;
    const int g = ((inner >> 3) << 3) + gc;
    const int cb = m * 96;
    const int n0 = (g % 24) * 96;
    const int bL = g / 24, b = bofs + bL;
    const unsigned short* xhb = xTh + (long)b * DD * NN;
    const unsigned short* xlb = xTl + (long)b * DD * NN;
    const unsigned short* phb = Ph + (long)bL * NN * NN;
    const unsigned short* plb = Pl + (long)bL * NN * NN;
    const unsigned short* srcArr = (w == 0) ? xhb : (w == 1) ? xlb
                                 : (w == 2) ? phb : plb;
    const int rbg = (w < 2) ? cb : n0;
    const int rl0 = lane >> 2, sl = lane & 3;

    f32x4 acc[3][3];
    #pragma unroll
    for (int ct = 0; ct < 3; ++ct)
        #pragma unroll
        for (int nt = 0; nt < 3; ++nt) acc[ct][nt] = 0.f;

#define STAGE(BUF_, K0_) do {                                                      \
    _Pragma("unroll")                                                              \
    for (int j = 0; j < 6; ++j) {                                                  \
        int rowL = j * 16 + rl0;                                                   \
        int koct = sl ^ ((rowL >> 1) & 3);                                         \
        __builtin_amdgcn_global_load_lds(                                          \
            (const __attribute__((address_space(1))) void*)                        \
                (srcArr + (long)(rbg + rowL) * NN + (K0_) + koct * 8),             \
            (__attribute__((address_space(3))) void*)&SM[BUF_][w][j * 512],        \
            16, 0, 0);                                                             \
    }                                                                              \
} while (0)

    STAGE(0, 0);
    for (int ph = 0; ph < NN / 32; ++ph) {
        const int buf = ph & 1;
        __builtin_amdgcn_s_barrier();             // all done reading buf^1
        {
            int kn = (ph + 1) * 32; if (kn >= NN) kn = 0;
            STAGE(buf ^ 1, kn);
        }
        asm volatile("s_waitcnt vmcnt(6)" ::: "memory");  // my phase-ph loads done
        __builtin_amdgcn_s_barrier();             // everyone's phase-ph loads done
        __builtin_amdgcn_sched_barrier(0);
        __builtin_amdgcn_s_setprio(1);
        {
            short8 pbh[3], pbl[3];
            #pragma unroll
            for (int nt = 0; nt < 3; ++nt) {
                int rl = wr * 48 + nt * 16 + l15;
                int so = rl * 32 + ((quad ^ ((rl >> 1) & 3)) * 8);
                pbh[nt] = *(const short8*)&SM[buf][2][so];
                pbl[nt] = *(const short8*)&SM[buf][3][so];
            }
            #pragma unroll
            for (int ct = 0; ct < 3; ++ct) {
                int cl = wc * 48 + ct * 16 + l15;
                int so = cl * 32 + ((quad ^ ((cl >> 1) & 3)) * 8);
                short8 axh = *(const short8*)&SM[buf][0][so];
                short8 axl = *(const short8*)&SM[buf][1][so];
                #pragma unroll
                for (int nt = 0; nt < 3; ++nt) {
                    acc[ct][nt] = MFMA(axh, pbh[nt], acc[ct][nt]);
                    acc[ct][nt] = MFMA(axl, pbh[nt], acc[ct][nt]);
                    acc[ct][nt] = MFMA(axh, pbl[nt], acc[ct][nt]);
                }
            }
        }
        __builtin_amdgcn_s_setprio(0);
    }
#undef STAGE

    float* OTb = OT + (long)b * DD * NN;
    #pragma unroll
    for (int nt = 0; nt < 3; ++nt) {
        int rowl = wr * 48 + nt * 16 + l15;
        int row = n0 + rowl;
        float linv = 1.f / lsumG[(long)b * NN + row];
        float s1 = 0.f, s2 = 0.f;
        #pragma unroll
        for (int ct = 0; ct < 3; ++ct)
            #pragma unroll
            for (int e = 0; e < 4; ++e) {
                float vv = acc[ct][nt][e] * linv;
                acc[ct][nt][e] = vv;
                s1 += vv; s2 += vv * vv;
            }
        s1 += __shfl_xor(s1, 16); s1 += __shfl_xor(s1, 32);
        s2 += __shfl_xor(s2, 16); s2 += __shfl_xor(s2, 32);
        #pragma unroll
        for (int ct = 0; ct < 3; ++ct)
            #pragma unroll
            for (int e = 0; e < 4; ++e)
                OTb[(long)(cb + wc * 48 + ct * 16 + quad * 4 + e) * NN + row] =
                    acc[ct][nt][e];
        if (lane < 16) {
            atomicAdd(&stats[((long)b * NN + row) * 2 + 0], s1);
            atomicAdd(&stats[((long)b * NN + row) * 2 + 1], s2);
        }
    }
}

// ===================== fallback fused attention (R3-v0, verified) ==================
#define ATTN_SETUP                                                                  \
    const int t = threadIdx.x;                                                      \
    const int w = t >> 6, lane = t & 63, quad = lane >> 4, l15 = lane & 15;         \
    const int bx = blockIdx.x;                                                      \
    const int combo = bx & 63, rt_idx = bx >> 6;                                    \
    const int b = combo & 7, g = combo >> 3;                                        \
    const int n0 = rt_idx * 96;                                                     \
    const int cb = g * 96;                                                          \
    const int sk = w & 1, sr = w >> 1;                                              \
    const int pbase = w * 1536;                                                     \
    if (t < 96) lsum[t] = 0.f;                                                      \
    const unsigned short* qhb = qhp + (long)b * NN * DM;                            \
    const unsigned short* qlb = qlp + (long)b * NN * DM;                            \
    const unsigned short* xhb = xTh + (long)b * DD * NN;                            \
    const unsigned short* xlb = xTl + (long)b * DD * NN;                            \
    short8 bh[3][2], bl[3][2];                                                      \
    _Pragma("unroll")                                                               \
    for (int rt = 0; rt < 3; ++rt) {                                                \
        _Pragma("unroll")                                                           \
        for (int kc = 0; kc < 2; ++kc) {                                            \
            long o = (long)(n0 + sr * 48 + rt * 16 + l15) * DM + kc * 32 + quad * 8;\
            bh[rt][kc] = *(const short8*)(qhb + o);                                 \
            bl[rt][kc] = *(const short8*)(qlb + o);                                 \
        }                                                                           \
    }                                                                               \
    float lp[3] = {0.f, 0.f, 0.f};                                                  \
    f32x4 acc[6][3];                                                                \
    _Pragma("unroll")                                                               \
    for (int ct = 0; ct < 6; ++ct) {                                                \
        _Pragma("unroll")                                                           \
        for (int nt = 0; nt < 3; ++nt) acc[ct][nt] = 0.f;                           \
    }

#define DMA_X(DH_, DL_, KB_) do {                                                   \
    _Pragma("unroll")                                                               \
    for (int j = 0; j < 6; ++j) {                                                   \
        int cg = w * 6 + j;                                                         \
        int cm = cg - (cg >= 12 ? 12 : 0);                                          \
        unsigned short* dstb = (cg < 12 ? (DH_) : (DL_)) + cm * 512;                \
        const unsigned short* srcb = (cg < 12 ? xhb : xlb);                         \
        int col = cm * 8 + (lane >> 3);                                             \
        int key = ((lane & 7) ^ (col & 7)) * 8;                                     \
        __builtin_amdgcn_global_load_lds(                                           \
            (const __attribute__((address_space(1))) void*)                         \
                (srcb + (long)(cb + col) * NN + (KB_) + key),                       \
            (__attribute__((address_space(3))) void*)dstb, 16, 0, 0);               \
    }                                                                               \
} while (0)

#define QPF(QN_, KQ_) do {                                                          \
    _Pragma("unroll")                                                               \
    for (int kt = 0; kt < 2; ++kt) {                                                \
        long o = (long)((KQ_) + sk * 32 + kt * 16 + l15) * DM + quad * 8;           \
        QN_[kt * 4 + 0] = *(const short8*)(qhb + o);                                \
        QN_[kt * 4 + 1] = *(const short8*)(qhb + o + 32);                           \
        QN_[kt * 4 + 2] = *(const short8*)(qlb + o);                                \
        QN_[kt * 4 + 3] = *(const short8*)(qlb + o + 32);                           \
    }                                                                               \
} while (0)

#define S_KT(QH0_, QH1_, QL0_, QL1_, KT_) do {                                      \
    _Pragma("unroll")                                                               \
    for (int rt = 0; rt < 3; ++rt) {                                                \
        f32x4 s = 0.f;                                                              \
        s = MFMA(QH0_, bh[rt][0], s);                                               \
        s = MFMA(QH1_, bh[rt][1], s);                                               \
        s = MFMA(QL0_, bh[rt][0], s);                                               \
        s = MFMA(QL1_, bh[rt][1], s);                                               \
        s = MFMA(QH0_, bl[rt][0], s);                                               \
        s = MFMA(QH1_, bl[rt][1], s);                                               \
        float p0 = __expf(s[0] * 0.125f);                                           \
        float p1 = __expf(s[1] * 0.125f);                                           \
        float p2 = __expf(s[2] * 0.125f);                                           \
        float p3 = __expf(s[3] * 0.125f);                                           \
        lp[rt] += (p0 + p1) + (p2 + p3);                                            \
        unsigned u0 = __float_as_uint(p0), u1 = __float_as_uint(p1);                \
        unsigned u2 = __float_as_uint(p2), u3 = __float_as_uint(p3);                \
        uint2v dh = { (u0 >> 16) | (u1 & 0xFFFF0000u),                              \
                      (u2 >> 16) | (u3 & 0xFFFF0000u) };                            \
        float r0 = p0 - __uint_as_float(u0 & 0xFFFF0000u);                          \
        float r1 = p1 - __uint_as_float(u1 & 0xFFFF0000u);                          \
        float r2 = p2 - __uint_as_float(u2 & 0xFFFF0000u);                          \
        float r3 = p3 - __uint_as_float(u3 & 0xFFFF0000u);                          \
        unsigned v0 = __float_as_uint(r0), v1 = __float_as_uint(r1);                \
        unsigned v2 = __float_as_uint(r2), v3 = __float_as_uint(r3);                \
        uint2v dl = { (v0 >> 16) | (v1 & 0xFFFF0000u),                              \
                      (v2 >> 16) | (v3 & 0xFFFF0000u) };                            \
        int rr_ = rt * 16 + l15;                                                    \
        int ff_ = (((rr_ & 7) ^ (rr_ >> 3)) & 7) << 2;                              \
        int ix_ = pbase + rr_ * 32 + (((KT_) * 16 + quad * 4) ^ ff_);               \
        *(uint2v*)&PHs[ix_] = dh;                                                   \
        *(uint2v*)&PLs[ix_] = dl;                                                   \
    }                                                                               \
} while (0)

#define PV_PHASE(XH_, XL_) do {                                                     \
    short8 pbh[3], pbl[3];                                                          \
    _Pragma("unroll")                                                               \
    for (int nt = 0; nt < 3; ++nt) {                                                \
        int r_ = nt * 16 + l15;                                                     \
        int ff_ = (((r_ & 7) ^ (r_ >> 3)) & 7) << 2;                                \
        int i0 = pbase + r_ * 32 + ((quad * 8) ^ ff_);                              \
        int i1 = pbase + r_ * 32 + ((quad * 8 + 4) ^ ff_);                          \
        short4v h0 = *(const short4v*)&PHs[i0];                                     \
        short4v h1 = *(const short4v*)&PHs[i1];                                     \
        short4v l0 = *(const short4v*)&PLs[i0];                                     \
        short4v l1 = *(const short4v*)&PLs[i1];                                     \
        pbh[nt] = __builtin_shufflevector(h0, h1, 0, 1, 2, 3, 4, 5, 6, 7);          \
        pbl[nt] = __builtin_shufflevector(l0, l1, 0, 1, 2, 3, 4, 5, 6, 7);          \
    }                                                                               \
    _Pragma("unroll")                                                               \
    for (int ct = 0; ct < 6; ++ct) {                                                \
        int colx = ct * 16 + l15;                                                   \
        int xk = (sk * 32 + quad * 8) ^ ((colx & 7) << 3);                          \
        short8 axh = *(const short8*)&(XH_)[colx * 64 + xk];                        \
        short8 axl = *(const short8*)&(XL_)[colx * 64 + xk];                        \
        _Pragma("unroll")                                                           \
        for (int nt = 0; nt < 3; ++nt) {                                            \
            acc[ct][nt] = MFMA(axh, pbh[nt], acc[ct][nt]);                          \
            acc[ct][nt] = MFMA(axl, pbh[nt], acc[ct][nt]);                          \
            acc[ct][nt] = MFMA(axh, pbl[nt], acc[ct][nt]);                          \
        }                                                                           \
    }                                                                               \
} while (0)

#define ATTN_EPILOGUE do {                                                          \
    _Pragma("unroll")                                                               \
    for (int rt = 0; rt < 3; ++rt) {                                                \
        float v = lp[rt];                                                           \
        v += __shfl_xor(v, 16); v += __shfl_xor(v, 32);                             \
        if (lane < 16) atomicAdd(&lsum[sr * 48 + rt * 16 + l15], v);                \
    }                                                                               \
    float* M = (float*)SMEM;                                                        \
    __syncthreads();                                                                \
    if (sk == 1) {                                                                  \
        float* Mw = M + sr * (48 * 100);                                            \
        _Pragma("unroll")                                                           \
        for (int nt = 0; nt < 3; ++nt) {                                            \
            _Pragma("unroll")                                                       \
            for (int ct = 0; ct < 6; ++ct)                                          \
                *(f32x4*)&Mw[(nt * 16 + l15) * 100 + ct * 16 + quad * 4] = acc[ct][nt]; \
        }                                                                           \
    }                                                                               \
    __syncthreads();                                                                \
    if (sk == 0) {                                                                  \
        const float* Mr = M + sr * (48 * 100);                                      \
        float* OTb = OT + (long)b * DD * NN;                                        \
        _Pragma("unroll")                                                           \
        for (int nt = 0; nt < 3; ++nt) {                                            \
            int rowl = sr * 48 + nt * 16 + l15;                                     \
            int row = n0 + rowl;                                                    \
            float linv = 1.f / lsum[rowl];                                          \
            float s1 = 0.f, s2 = 0.f;                                               \
            _Pragma("unroll")                                                       \
            for (int ct = 0; ct < 6; ++ct) {                                        \
                f32x4 pq = *(const f32x4*)&Mr[(nt * 16 + l15) * 100 + ct * 16 + quad * 4]; \
                _Pragma("unroll")                                                   \
                for (int e = 0; e < 4; ++e) {                                       \
                    float vv = (acc[ct][nt][e] + pq[e]) * linv;                     \
                    acc[ct][nt][e] = vv;                                            \
                    s1 += vv; s2 += vv * vv;                                        \
                }                                                                   \
            }                                                                       \
            s1 += __shfl_xor(s1, 16); s1 += __shfl_xor(s1, 32);                     \
            s2 += __shfl_xor(s2, 16); s2 += __shfl_xor(s2, 32);                     \
            _Pragma("unroll")                                                       \
            for (int ct = 0; ct < 6; ++ct) {                                        \
                _Pragma("unroll")                                                   \
                for (int e = 0; e < 4; ++e)                                         \
                    OTb[(long)(cb + ct * 16 + quad * 4 + e) * NN + row] = acc[ct][nt][e]; \
            }                                                                       \
            if (lane < 16) {                                                        \
                atomicAdd(&stats[((long)b * NN + row) * 2 + 0], s1);                \
                atomicAdd(&stats[((long)b * NN + row) * 2 + 1], s2);                \
            }                                                                       \
        }                                                                           \
    }                                                                               \
} while (0)

__global__ __launch_bounds__(256, 2) void attn_v0(
        const unsigned short* __restrict__ qhp, const unsigned short* __restrict__ qlp,
        const unsigned short* __restrict__ xTh, const unsigned short* __restrict__ xTl,
        float* __restrict__ OT, float* __restrict__ stats) {
    __shared__ __align__(16) unsigned char SMEM[49536];
    unsigned short* XHs = (unsigned short*)SMEM;
    unsigned short* XLs = XHs + 6144;
    unsigned short* PHs = XHs + 12288;
    unsigned short* PLs = XHs + 18432;
    float* lsum = (float*)(SMEM + 49152);
    ATTN_SETUP;
    short8 qA[8], qB[8];
    QPF(qA, 0);
    for (int kp = 0; kp < NN; kp += 128) {
        __syncthreads();
        DMA_X(XHs, XLs, kp);
        { int kq = kp + 64; QPF(qB, kq); }
        S_KT(qA[0], qA[1], qA[2], qA[3], 0);
        S_KT(qA[4], qA[5], qA[6], qA[7], 1);
        __syncthreads();
        __builtin_amdgcn_s_setprio(1);
        PV_PHASE(XHs, XLs);
        __builtin_amdgcn_s_setprio(0);
        __syncthreads();
        DMA_X(XHs, XLs, kp + 64);
        { int kq = kp + 128; if (kq >= NN) kq = 0; QPF(qA, kq); }
        S_KT(qB[0], qB[1], qB[2], qB[3], 0);
        S_KT(qB[4], qB[5], qB[6], qB[7], 1);
        __syncthreads();
        __builtin_amdgcn_s_setprio(1);
        PV_PHASE(XHs, XLs);
        __builtin_amdgcn_s_setprio(0);
    }
    ATTN_EPILOGUE;
}

// ---------- LN apply (mid layers): O^T fp32 -> split-bf16 xT ------------------------
__global__ __launch_bounds__(256) void lncvt_mid_kernel(
        const float* __restrict__ OT, const float* __restrict__ stats,
        const float* __restrict__ gamma, const float* __restrict__ beta,
        unsigned short* __restrict__ xTh, unsigned short* __restrict__ xTl) {
    int t = threadIdx.x;
    int n = blockIdx.x * 64 + (t & 63);
    int b = blockIdx.z;
    int c0 = blockIdx.y * 192 + (t >> 6);
    float s1 = stats[((long)b * NN + n) * 2 + 0];
    float s2 = stats[((long)b * NN + n) * 2 + 1];
    float mu = s1 * (1.f / 768.f);
    float rs = rsqrtf(s2 * (1.f / 768.f) - mu * mu + EPSF);
    const float* OTb = OT + (long)b * DD * NN;
    #pragma unroll 4
    for (int i = 0; i < 48; ++i) {
        int c = c0 + i * 4;
        float o = OTb[(long)c * NN + n];
        float y = (o - mu) * rs * gamma[c] + beta[c];
        unsigned short h = f2b(y);
        long idx = ((long)b * DD + c) * NN + n;
        xTh[idx] = h;
        xTl[idx] = f2b(y - b2f(h));
    }
}

// ---------- LN apply (final): O^T fp32 -> out fp32 [B][N][D] via LDS transpose ------
__global__ __launch_bounds__(256) void lncvt_final_kernel(
        const float* __restrict__ OT, const float* __restrict__ stats,
        const float* __restrict__ gamma, const float* __restrict__ beta,
        float* __restrict__ out) {
    __shared__ float T[64][65];
    int t = threadIdx.x;
    int nl = t & 63, cw = t >> 6;
    int b = blockIdx.y, n0 = blockIdx.x * 64;
    int n = n0 + nl;
    float s1 = stats[((long)b * NN + n) * 2 + 0];
    float s2 = stats[((long)b * NN + n) * 2 + 1];
    float mu = s1 * (1.f / 768.f);
    float rs = rsqrtf(s2 * (1.f / 768.f) - mu * mu + EPSF);
    const float* OTb = OT + (long)b * DD * NN;
    float* ob = out + (long)b * NN * DD;
    int row_l = t >> 2, seg = t & 3;
    for (int ct = 0; ct < 12; ++ct) {
        #pragma unroll
        for (int i = 0; i < 16; ++i) {
            int cl = cw + i * 4;
            int c = ct * 64 + cl;
            float o = OTb[(long)c * NN + n];
            T[nl][cl] = (o - mu) * rs * gamma[c] + beta[c];
        }
        __syncthreads();
        #pragma unroll
        for (int i = 0; i < 4; ++i) {
            int cl = seg * 16 + i * 4;
            float4 v = *(const float4*)&T[row_l][cl];
            *(float4*)&ob[(long)(n0 + row_l) * DD + ct * 64 + cl] = v;
        }
        __syncthreads();
    }
}

extern "C" void kernel_launch(void* const* d_in, const int* in_sizes, int n_in,
                              void* d_out, int out_size, void* d_ws, size_t ws_size,
                              hipStream_t stream) {
    (void)in_sizes; (void)n_in; (void)out_size;
    const float* x     = (const float*)d_in[0];
    const float* Wq    = (const float*)d_in[1];
    const float* bq    = (const float*)d_in[2];
    const float* gamma = (const float*)d_in[3];
    const float* beta  = (const float*)d_in[4];
    float* out = (float*)d_out;

    char* p = (char*)d_ws;
    const size_t szXT = (size_t)BB * DD * NN * 2;          // 28.3 MB
    unsigned short* xTh = (unsigned short*)p; p += szXT;
    unsigned short* xTl = (unsigned short*)p; p += szXT;
    float* OT           = (float*)p;          p += (size_t)BB * DD * NN * 4;   // 56.6 MB
    unsigned short* qh  = (unsigned short*)p; p += (size_t)BB * NN * DM * 2;
    unsigned short* ql  = (unsigned short*)p; p += (size_t)BB * NN * DM * 2;
    float* stats        = (float*)p;          p += (size_t)BB * NN * 2 * 4;
    float* lsumG        = (float*)p;          p += (size_t)BB * NN * 4;   // after stats!
    unsigned short* Wth = (unsigned short*)p; p += (size_t)DM * DD * 2;
    unsigned short* Wtl = (unsigned short*)p; p += (size_t)DM * DD * 2;

    // per-batch P (hi+lo) from the remaining workspace; choose group size gb
    size_t used = (size_t)(p - (char*)d_ws);
    const size_t perB = (size_t)NN * NN * 2 * 2;           // 21.2 MB per batch
    int gb = 0;
    if      (ws_size >= used + 8 * perB) gb = 8;
    else if (ws_size >= used + 4 * perB) gb = 4;
    else if (ws_size >= used + 2 * perB) gb = 2;
    else if (ws_size >= used + 1 * perB) gb = 1;
    unsigned short* Ph = (unsigned short*)p;
    unsigned short* Pl = Ph + (size_t)(gb > 0 ? gb : 1) * NN * NN;

    cvt_kernel<<<dim3(NN / 64, DD / 64, BB), 256, 0, stream>>>(x, xTh, xTl);
    wqcvt_kernel<<<dim3(DD * DM / 256), 256, 0, stream>>>(Wq, Wth, Wtl);

    for (int layer = 0; layer < 3; ++layer) {
        proj_kernel<<<dim3(NN / 64, BB), 256, 0, stream>>>(Wth, Wtl, xTh, xTl, bq, qh, ql);
        zstats_kernel<<<dim3(BB * NN * 3 / 256), 256, 0, stream>>>(stats); // stats+lsumG
        if (gb > 0) {
            for (int g0 = 0; g0 < BB; g0 += gb) {
                qk_kernel<<<dim3(NN / 96, 12, gb), 256, 0, stream>>>(
                    qh, ql, Ph, Pl, lsumG, g0);
                if (layer < 2)
                    pv_lds128<<<dim3((DD / 128) * (NN / 128) * gb), 256, 0, stream>>>(
                        Ph, Pl, xTh, xTl, lsumG, OT, stats, g0);
                else
                    pv_lds<<<dim3(8 * (NN / 96) * gb), 256, 0, stream>>>(
                        Ph, Pl, xTh, xTl, lsumG, OT, stats, g0);
            }
        } else {
            attn_v0<<<dim3(24 * 64), 256, 0, stream>>>(qh, ql, xTh, xTl, OT, stats);
        }
        if (layer < 2)
            lncvt_mid_kernel<<<dim3(NN / 64, 4, BB), 256, 0, stream>>>(OT, stats, gamma, beta, xTh, xTl);
        else
            lncvt_final_kernel<<<dim3(NN / 64, BB), 256, 0, stream>>>(OT, stats, gamma, beta, out);
    }
}

// Round 10
// 1199.072 us; speedup vs baseline: 1.6517x; 1.0102x over previous
//
#include <hip/hip_runtime.h>
#include <math.h>

#define BB 8
#define NN 2304
#define DD 768
#define DM 64
#define EPSF 1e-5f

typedef __attribute__((ext_vector_type(8))) short short8;   // 8 x bf16 bits (16 B)
typedef __attribute__((ext_vector_type(4))) short short4v;  // 4 x bf16 bits (8 B)
typedef __attribute__((ext_vector_type(4))) float f32x4;
typedef __attribute__((ext_vector_type(2))) unsigned int uint2v;

static __device__ __forceinline__ unsigned short f2b(float f) {
    unsigned u = __float_as_uint(f);
    unsigned r = u + 0x7FFFu + ((u >> 16) & 1u);
    return (unsigned short)(r >> 16);
}
static __device__ __forceinline__ float b2f(unsigned short h) {
    return __uint_as_float(((unsigned)h) << 16);
}
#define MFMA(a, b, c) __builtin_amdgcn_mfma_f32_16x16x32_bf16((a), (b), (c), 0, 0, 0)

// ---------- layer-0: fp32 x [B][N][D] -> split-bf16 transposed xT_hi/lo [B][D][N] ----
__global__ __launch_bounds__(256) void cvt_kernel(const float* __restrict__ xf,
                                                  unsigned short* __restrict__ xTh,
                                                  unsigned short* __restrict__ xTl) {
    __shared__ __align__(16) unsigned short Th[64][72];
    __shared__ __align__(16) unsigned short Tl[64][72];
    int t = threadIdx.x;
    int b = blockIdx.z;
    int n0 = blockIdx.x * 64, c0 = blockIdx.y * 64;
    int rr = t >> 4, cc = (t & 15) * 4;
    #pragma unroll
    for (int i = 0; i < 4; ++i) {
        int r = rr + i * 16;
        long idx = ((long)b * NN + n0 + r) * DD + c0 + cc;
        float4 v = *(const float4*)&xf[idx];
        unsigned short h0 = f2b(v.x), h1 = f2b(v.y), h2 = f2b(v.z), h3 = f2b(v.w);
        Th[cc + 0][r] = h0; Th[cc + 1][r] = h1; Th[cc + 2][r] = h2; Th[cc + 3][r] = h3;
        Tl[cc + 0][r] = f2b(v.x - b2f(h0));
        Tl[cc + 1][r] = f2b(v.y - b2f(h1));
        Tl[cc + 2][r] = f2b(v.z - b2f(h2));
        Tl[cc + 3][r] = f2b(v.w - b2f(h3));
    }
    __syncthreads();
    #pragma unroll
    for (int i = 0; i < 4; ++i) {
        int c = rr + i * 16;
        long idx = ((long)b * DD + c0 + c) * NN + n0 + cc;
        *(ushort4*)&xTh[idx] = *(const ushort4*)&Th[c][cc];
        *(ushort4*)&xTl[idx] = *(const ushort4*)&Tl[c][cc];
    }
}

// ---------- Wq fp32 [768][64] -> transposed split bf16 Wt_hi/lo [64][768] ----------
__global__ __launch_bounds__(256) void wqcvt_kernel(const float* __restrict__ Wq,
                                                    unsigned short* __restrict__ Wth,
                                                    unsigned short* __restrict__ Wtl) {
    int t = blockIdx.x * 256 + threadIdx.x;   // t < 768*64
    int d = t >> 6, m = t & 63;
    float v = Wq[t];
    unsigned short h = f2b(v);
    Wth[m * DD + d] = h;
    Wtl[m * DD + d] = f2b(v - b2f(h));
}

// zeroes stats (2 floats/row) + lsumG (1 float/row), contiguous: 3*BB*NN floats
__global__ __launch_bounds__(256) void zstats_kernel(float* __restrict__ stats) {
    stats[blockIdx.x * 256 + threadIdx.x] = 0.f;
}

// ---------- MFMA q-projection ------------------------------------------------------
__global__ __launch_bounds__(256) void proj_kernel(
        const unsigned short* __restrict__ Wth, const unsigned short* __restrict__ Wtl,
        const unsigned short* __restrict__ xTh, const unsigned short* __restrict__ xTl,
        const float* __restrict__ bq,
        unsigned short* __restrict__ qh, unsigned short* __restrict__ ql) {
    int t = threadIdx.x;
    int w = t >> 6, lane = t & 63, quad = lane >> 4, l15 = lane & 15;
    int n0 = blockIdx.x * 64, b = blockIdx.y;
    const unsigned short* xhb = xTh + (long)b * DD * NN;
    const unsigned short* xlb = xTl + (long)b * DD * NN;

    f32x4 accQ[4];
    #pragma unroll
    for (int nt = 0; nt < 4; ++nt) accQ[nt] = 0.f;

    for (int d0 = 0; d0 < DD; d0 += 32) {
        short8 ah = *(const short8*)&Wth[(w * 16 + l15) * DD + d0 + quad * 8];
        short8 al = *(const short8*)&Wtl[(w * 16 + l15) * DD + d0 + quad * 8];
        #pragma unroll
        for (int nt = 0; nt < 4; ++nt) {
            int row = n0 + nt * 16 + l15;
            short8 bh, bl;
            #pragma unroll
            for (int j = 0; j < 8; ++j) {
                long o = (long)(d0 + quad * 8 + j) * NN + row;
                bh[j] = (short)xhb[o];
                bl[j] = (short)xlb[o];
            }
            accQ[nt] = MFMA(ah, bh, accQ[nt]);
            accQ[nt] = MFMA(al, bh, accQ[nt]);
            accQ[nt] = MFMA(ah, bl, accQ[nt]);
        }
    }
    #pragma unroll
    for (int nt = 0; nt < 4; ++nt) {
        int row = n0 + nt * 16 + l15;
        #pragma unroll
        for (int e = 0; e < 4; ++e) {
            int qm = w * 16 + quad * 4 + e;
            float v = accQ[nt][e] + bq[qm];
            unsigned short h = f2b(v);
            long o = ((long)b * NN + row) * DM + qm;
            qh[o] = h;
            ql[o] = f2b(v - b2f(h));
        }
    }
}

// ============ kernel A: S = q.q^T, exp, split-bf16 pack -> global P ================
// P computed once per (b,row). Coalesced stores via wave-private swizzled LDS
// staging. grid (24, 12, gb): 192 keys/block (3 iters) for occupancy; 4 waves.
__global__ __launch_bounds__(256) void qk_kernel(
        const unsigned short* __restrict__ qhp, const unsigned short* __restrict__ qlp,
        unsigned short* __restrict__ Ph, unsigned short* __restrict__ Pl,
        float* __restrict__ lsumG, int bofs) {
    __shared__ __align__(16) unsigned short PHs[4 * 1536];  // [wave][48r x 32k]
    __shared__ __align__(16) unsigned short PLs[4 * 1536];
    const int t = threadIdx.x;
    const int w = t >> 6, lane = t & 63, quad = lane >> 4, l15 = lane & 15;
    const int sk = w & 1, sr = w >> 1;
    const int pbase = w * 1536;
    const int n0 = blockIdx.x * 96;
    const int k00 = blockIdx.y * 192;
    const int bL = blockIdx.z, b = bofs + bL;
    const unsigned short* qhb = qhp + (long)b * NN * DM;
    const unsigned short* qlb = qlp + (long)b * NN * DM;

    short8 bh[3][2], bl[3][2];
    #pragma unroll
    for (int rt = 0; rt < 3; ++rt)
        #pragma unroll
        for (int kc = 0; kc < 2; ++kc) {
            long o = (long)(n0 + sr * 48 + rt * 16 + l15) * DM + kc * 32 + quad * 8;
            bh[rt][kc] = *(const short8*)(qhb + o);
            bl[rt][kc] = *(const short8*)(qlb + o);
        }
    float lp[3] = {0.f, 0.f, 0.f};

    for (int k0 = k00; k0 < k00 + 192; k0 += 64) {
        #pragma unroll
        for (int kt = 0; kt < 2; ++kt) {
            long ao = (long)(k0 + sk * 32 + kt * 16 + l15) * DM + quad * 8;
            short8 qh0 = *(const short8*)(qhb + ao);
            short8 qh1 = *(const short8*)(qhb + ao + 32);
            short8 ql0 = *(const short8*)(qlb + ao);
            short8 ql1 = *(const short8*)(qlb + ao + 32);
            #pragma unroll
            for (int rt = 0; rt < 3; ++rt) {
                f32x4 s = 0.f;
                s = MFMA(qh0, bh[rt][0], s);
                s = MFMA(qh1, bh[rt][1], s);
                s = MFMA(ql0, bh[rt][0], s);
                s = MFMA(ql1, bh[rt][1], s);
                s = MFMA(qh0, bl[rt][0], s);
                s = MFMA(qh1, bl[rt][1], s);
                float p0 = __expf(s[0] * 0.125f);
                float p1 = __expf(s[1] * 0.125f);
                float p2 = __expf(s[2] * 0.125f);
                float p3 = __expf(s[3] * 0.125f);
                lp[rt] += (p0 + p1) + (p2 + p3);
                unsigned u0 = __float_as_uint(p0), u1 = __float_as_uint(p1);
                unsigned u2 = __float_as_uint(p2), u3 = __float_as_uint(p3);
                uint2v dh = { (u0 >> 16) | (u1 & 0xFFFF0000u),
                              (u2 >> 16) | (u3 & 0xFFFF0000u) };
                float r0 = p0 - __uint_as_float(u0 & 0xFFFF0000u);
                float r1 = p1 - __uint_as_float(u1 & 0xFFFF0000u);
                float r2 = p2 - __uint_as_float(u2 & 0xFFFF0000u);
                float r3 = p3 - __uint_as_float(u3 & 0xFFFF0000u);
                unsigned v0 = __float_as_uint(r0), v1 = __float_as_uint(r1);
                unsigned v2 = __float_as_uint(r2), v3 = __float_as_uint(r3);
                uint2v dl = { (v0 >> 16) | (v1 & 0xFFFF0000u),
                              (v2 >> 16) | (v3 & 0xFFFF0000u) };
                int rr = rt * 16 + l15;
                int ff = (((rr & 7) ^ (rr >> 3)) & 7) << 2;
                int ix = pbase + rr * 32 + ((kt * 16 + quad * 4) ^ ff);
                *(uint2v*)&PHs[ix] = dh;
                *(uint2v*)&PLs[ix] = dl;
            }
        }
        // readback (undo swizzle) + coalesced 16B stores: 4 lanes = 64B per row
        #pragma unroll
        for (int r = 0; r < 3; ++r) {
            int c = r * 64 + lane;          // 192 chunks = 48 rows x 4 segs
            int rr = c >> 2, s = c & 3;
            int ff = (((rr & 7) ^ (rr >> 3)) & 7) << 2;
            int i0 = pbase + rr * 32 + ((s * 8) ^ ff);
            int i1 = pbase + rr * 32 + ((s * 8 + 4) ^ ff);
            short4v h0 = *(const short4v*)&PHs[i0];
            short4v h1 = *(const short4v*)&PHs[i1];
            short4v l0 = *(const short4v*)&PLs[i0];
            short4v l1 = *(const short4v*)&PLs[i1];
            short8 hh = __builtin_shufflevector(h0, h1, 0, 1, 2, 3, 4, 5, 6, 7);
            short8 ll = __builtin_shufflevector(l0, l1, 0, 1, 2, 3, 4, 5, 6, 7);
            long po = ((long)bL * NN + n0 + sr * 48 + rr) * NN + k0 + sk * 32 + s * 8;
            *(short8*)&Ph[po] = hh;
            *(short8*)&Pl[po] = ll;
        }
    }
    #pragma unroll
    for (int rt = 0; rt < 3; ++rt) {
        float v = lp[rt];
        v += __shfl_xor(v, 16); v += __shfl_xor(v, 32);
        if (lane < 16)
            atomicAdd(&lsumG[(long)b * NN + n0 + sr * 48 + rt * 16 + l15], v);
    }
}

// ============ kernel B variant 1: pv_lds128i — interleaved read/MFMA schedule ======
// R9 established full LDS/MFMA serialization (wall = LDS + MFMA cycles summed): all
// waves' read bursts align after the barrier, so no wave MFMAs until the whole burst
// drains. Fix: first MFMA needs only 2 reads; alternate {2 ds_read -> 1-3 MFMA}
// through the 16 reads / 48 MFMAs, pinned with sched_group_barrier (DS_READ=0x100,
// MFMA=0x8) so the scheduler can't hoist reads back into a burst. Compiler owns all
// lgkmcnt (no inline-asm waits). DMA/vmcnt(8)/barrier skeleton unchanged (R5-proven).
__global__ __launch_bounds__(256, 2) void pv_lds128(
        const unsigned short* __restrict__ Ph, const unsigned short* __restrict__ Pl,
        const unsigned short* __restrict__ xTh, const unsigned short* __restrict__ xTl,
        const float* __restrict__ lsumG, float* __restrict__ OT,
        float* __restrict__ stats, int bofs) {
    __shared__ __align__(16) unsigned short SM[2][4][4096];  // [buf][arr][128 x 32k]
    const int t = threadIdx.x;
    const int w = t >> 6, lane = t & 63, quad = lane >> 4, l15 = lane & 15;
    const int wc = w & 1, wr = w >> 1;
    const int B = blockIdx.x;
    const int nwg = gridDim.x;
    int logical;
    if ((nwg & 7) == 0) { int chunk = nwg >> 3; logical = (B & 7) * chunk + (B >> 3); }
    else logical = B;
    const int m = logical % (DD / 128);
    const int rest = logical / (DD / 128);
    const int n0i = rest % (NN / 128);
    const int bL = rest / (NN / 128), b = bofs + bL;
    const int cb = m * 128;
    const int n0 = n0i * 128;
    const unsigned short* xhb = xTh + (long)b * DD * NN;
    const unsigned short* xlb = xTl + (long)b * DD * NN;
    const unsigned short* phb = Ph + (long)bL * NN * NN;
    const unsigned short* plb = Pl + (long)bL * NN * NN;
    const unsigned short* srcArr = (w == 0) ? xhb : (w == 1) ? xlb
                                 : (w == 2) ? phb : plb;
    const int rbg = (w < 2) ? cb : n0;
    const int rl0 = lane >> 2, sl = lane & 3;

    f32x4 acc[4][4];
    #pragma unroll
    for (int ct = 0; ct < 4; ++ct)
        #pragma unroll
        for (int nt = 0; nt < 4; ++nt) acc[ct][nt] = 0.f;

    int pso[4], xso[4];
    #pragma unroll
    for (int nt = 0; nt < 4; ++nt) {
        int rl = wr * 64 + nt * 16 + l15;
        pso[nt] = rl * 32 + ((quad ^ ((rl >> 1) & 3)) * 8);
    }
    #pragma unroll
    for (int ct = 0; ct < 4; ++ct) {
        int cl = wc * 64 + ct * 16 + l15;
        xso[ct] = cl * 32 + ((quad ^ ((cl >> 1) & 3)) * 8);
    }

    // store key-octet swizzled by ((row>>1)&3); read with matching XOR (R5-verified)
#define STAGE(BUF_, K0_) do {                                                      \
    _Pragma("unroll")                                                              \
    for (int j = 0; j < 8; ++j) {                                                  \
        int rowL = j * 16 + rl0;                                                   \
        int koct = sl ^ ((rowL >> 1) & 3);                                         \
        __builtin_amdgcn_global_load_lds(                                          \
            (const __attribute__((address_space(1))) void*)                        \
                (srcArr + (long)(rbg + rowL) * NN + (K0_) + koct * 8),             \
            (__attribute__((address_space(3))) void*)&SM[BUF_][w][j * 512],        \
            16, 0, 0);                                                             \
    }                                                                              \
} while (0)
#define SGB_R(N_) __builtin_amdgcn_sched_group_barrier(0x100, N_, 0)
#define SGB_M(N_) __builtin_amdgcn_sched_group_barrier(0x008, N_, 0)

    STAGE(0, 0);
    for (int ph = 0; ph < NN / 32; ++ph) {
        const int buf = ph & 1;
        __builtin_amdgcn_s_barrier();             // all done reading buf^1
        {
            int kn = (ph + 1) * 32; if (kn >= NN) kn = 0;
            STAGE(buf ^ 1, kn);
        }
        asm volatile("s_waitcnt vmcnt(8)" ::: "memory");  // my phase-ph loads done
        __builtin_amdgcn_s_barrier();             // everyone's phase-ph loads done
        __builtin_amdgcn_sched_barrier(0);
        __builtin_amdgcn_s_setprio(1);
        {
            short8 pbh[4], pbl[4], axh[4], axl[4];
            // --- warm-up: 2 reads -> 1 MFMA, then trickle reads between MFMAs ---
            pbh[0] = *(const short8*)&SM[buf][2][pso[0]];
            axh[0] = *(const short8*)&SM[buf][0][xso[0]];
            SGB_R(2);
            acc[0][0] = MFMA(axh[0], pbh[0], acc[0][0]);
            SGB_M(1);
            pbl[0] = *(const short8*)&SM[buf][3][pso[0]];
            axl[0] = *(const short8*)&SM[buf][1][xso[0]];
            SGB_R(2);
            acc[0][0] = MFMA(axl[0], pbh[0], acc[0][0]);
            acc[0][0] = MFMA(axh[0], pbl[0], acc[0][0]);
            SGB_M(2);
            #pragma unroll
            for (int nt = 1; nt < 4; ++nt) {
                pbh[nt] = *(const short8*)&SM[buf][2][pso[nt]];
                pbl[nt] = *(const short8*)&SM[buf][3][pso[nt]];
                SGB_R(2);
                acc[0][nt] = MFMA(axh[0], pbh[nt], acc[0][nt]);
                acc[0][nt] = MFMA(axl[0], pbh[nt], acc[0][nt]);
                acc[0][nt] = MFMA(axh[0], pbl[nt], acc[0][nt]);
                SGB_M(3);
            }
            #pragma unroll
            for (int ct = 1; ct < 4; ++ct) {
                axh[ct] = *(const short8*)&SM[buf][0][xso[ct]];
                axl[ct] = *(const short8*)&SM[buf][1][xso[ct]];
                SGB_R(2);
                #pragma unroll
                for (int nt = 0; nt < 4; ++nt) {
                    acc[ct][nt] = MFMA(axh[ct], pbh[nt], acc[ct][nt]);
                    acc[ct][nt] = MFMA(axl[ct], pbh[nt], acc[ct][nt]);
                    acc[ct][nt] = MFMA(axh[ct], pbl[nt], acc[ct][nt]);
                    SGB_M(3);
                }
            }
        }
        __builtin_amdgcn_s_setprio(0);
    }
#undef STAGE
#undef SGB_R
#undef SGB_M

    float* OTb = OT + (long)b * DD * NN;
    #pragma unroll
    for (int nt = 0; nt < 4; ++nt) {
        int rowl = wr * 64 + nt * 16 + l15;
        int row = n0 + rowl;
        float linv = 1.f / lsumG[(long)b * NN + row];
        float s1 = 0.f, s2 = 0.f;
        #pragma unroll
        for (int ct = 0; ct < 4; ++ct)
            #pragma unroll
            for (int e = 0; e < 4; ++e) {
                float vv = acc[ct][nt][e] * linv;
                acc[ct][nt][e] = vv;
                s1 += vv; s2 += vv * vv;
            }
        s1 += __shfl_xor(s1, 16); s1 += __shfl_xor(s1, 32);
        s2 += __shfl_xor(s2, 16); s2 += __shfl_xor(s2, 32);
        #pragma unroll
        for (int ct = 0; ct < 4; ++ct)
            #pragma unroll
            for (int e = 0; e < 4; ++e)
                OTb[(long)(cb + wc * 64 + ct * 16 + quad * 4 + e) * NN + row] =
                    acc[ct][nt][e];
        if (lane < 16) {
            atomicAdd(&stats[((long)b * NN + row) * 2 + 0], s1);
            atomicAdd(&stats[((long)b * NN + row) * 2 + 1], s2);
        }
    }
}

// ============ kernel B variant 2: pv_lds — R5 verified (124us control) =============
__global__ __launch_bounds__(256, 3) void pv_lds(
        const unsigned short* __restrict__ Ph, const unsigned short* __restrict__ Pl,
        const unsigned short* __restrict__ xTh, const unsigned short* __restrict__ xTl,
        const float* __restrict__ lsumG, float* __restrict__ OT,
        float* __restrict__ stats, int bofs) {
    __shared__ __align__(16) unsigned short SM[2][4][3072];  // [buf][arr][96r x 32k]
    const int t = threadIdx.x;
    const int w = t >> 6, lane = t & 63, quad = lane >> 4, l15 = lane & 15;
    const int wc = w & 1, wr = w >> 1;
    const int phys = blockIdx.x;
    const int gc = phys & 7;
    const int inner = phys >> 3;
    const int m = inner & 7;
    const int g = ((inner >> 3) << 3) + gc;
    const int cb = m * 96;
    const int n0 = (g % 24) * 96;
    const int bL = g / 24, b = bofs + bL;
    const unsigned short* xhb = xTh + (long)b * DD * NN;
    const unsigned short* xlb = xTl + (long)b * DD * NN;
    const unsigned short* phb = Ph + (long)bL * NN * NN;
    const unsigned short* plb = Pl + (long)bL * NN * NN;
    const unsigned short* srcArr = (w == 0) ? xhb : (w == 1) ? xlb
                                 : (w == 2) ? phb : plb;
    const int rbg = (w < 2) ? cb : n0;
    const int rl0 = lane >> 2, sl = lane & 3;

    f32x4 acc[3][3];
    #pragma unroll
    for (int ct = 0; ct < 3; ++ct)
        #pragma unroll
        for (int nt = 0; nt < 3; ++nt) acc[ct][nt] = 0.f;

#define STAGE(BUF_, K0_) do {                                                      \
    _Pragma("unroll")                                                              \
    for (int j = 0; j < 6; ++j) {                                                  \
        int rowL = j * 16 + rl0;                                                   \
        int koct = sl ^ ((rowL >> 1) & 3);                                         \
        __builtin_amdgcn_global_load_lds(                                          \
            (const __attribute__((address_space(1))) void*)                        \
                (srcArr + (long)(rbg + rowL) * NN + (K0_) + koct * 8),             \
            (__attribute__((address_space(3))) void*)&SM[BUF_][w][j * 512],        \
            16, 0, 0);                                                             \
    }                                                                              \
} while (0)

    STAGE(0, 0);
    for (int ph = 0; ph < NN / 32; ++ph) {
        const int buf = ph & 1;
        __builtin_amdgcn_s_barrier();             // all done reading buf^1
        {
            int kn = (ph + 1) * 32; if (kn >= NN) kn = 0;
            STAGE(buf ^ 1, kn);
        }
        asm volatile("s_waitcnt vmcnt(6)" ::: "memory");  // my phase-ph loads done
        __builtin_amdgcn_s_barrier();             // everyone's phase-ph loads done
        __builtin_amdgcn_sched_barrier(0);
        __builtin_amdgcn_s_setprio(1);
        {
            short8 pbh[3], pbl[3];
            #pragma unroll
            for (int nt = 0; nt < 3; ++nt) {
                int rl = wr * 48 + nt * 16 + l15;
                int so = rl * 32 + ((quad ^ ((rl >> 1) & 3)) * 8);
                pbh[nt] = *(const short8*)&SM[buf][2][so];
                pbl[nt] = *(const short8*)&SM[buf][3][so];
            }
            #pragma unroll
            for (int ct = 0; ct < 3; ++ct) {
                int cl = wc * 48 + ct * 16 + l15;
                int so = cl * 32 + ((quad ^ ((cl >> 1) & 3)) * 8);
                short8 axh = *(const short8*)&SM[buf][0][so];
                short8 axl = *(const short8*)&SM[buf][1][so];
                #pragma unroll
                for (int nt = 0; nt < 3; ++nt) {
                    acc[ct][nt] = MFMA(axh, pbh[nt], acc[ct][nt]);
                    acc[ct][nt] = MFMA(axl, pbh[nt], acc[ct][nt]);
                    acc[ct][nt] = MFMA(axh, pbl[nt], acc[ct][nt]);
                }
            }
        }
        __builtin_amdgcn_s_setprio(0);
    }
#undef STAGE

    float* OTb = OT + (long)b * DD * NN;
    #pragma unroll
    for (int nt = 0; nt < 3; ++nt) {
        int rowl = wr * 48 + nt * 16 + l15;
        int row = n0 + rowl;
        float linv = 1.f / lsumG[(long)b * NN + row];
        float s1 = 0.f, s2 = 0.f;
        #pragma unroll
        for (int ct = 0; ct < 3; ++ct)
            #pragma unroll
            for (int e = 0; e < 4; ++e) {
                float vv = acc[ct][nt][e] * linv;
                acc[ct][nt][e] = vv;
                s1 += vv; s2 += vv * vv;
            }
        s1 += __shfl_xor(s1, 16); s1 += __shfl_xor(s1, 32);
        s2 += __shfl_xor(s2, 16); s2 += __shfl_xor(s2, 32);
        #pragma unroll
        for (int ct = 0; ct < 3; ++ct)
            #pragma unroll
            for (int e = 0; e < 4; ++e)
                OTb[(long)(cb + wc * 48 + ct * 16 + quad * 4 + e) * NN + row] =
                    acc[ct][nt][e];
        if (lane < 16) {
            atomicAdd(&stats[((long)b * NN + row) * 2 + 0], s1);
            atomicAdd(&stats[((long)b * NN + row) * 2 + 1], s2);
        }
    }
}

// ===================== fallback fused attention (R3-v0, verified) ==================
#define ATTN_SETUP                                                                  \
    const int t = threadIdx.x;                                                      \
    const int w = t >> 6, lane = t & 63, quad = lane >> 4, l15 = lane & 15;         \
    const int bx = blockIdx.x;                                                      \
    const int combo = bx & 63, rt_idx = bx >> 6;                                    \
    const int b = combo & 7, g = combo >> 3;                                        \
    const int n0 = rt_idx * 96;                                                     \
    const int cb = g * 96;                                                          \
    const int sk = w & 1, sr = w >> 1;                                              \
    const int pbase = w * 1536;                                                     \
    if (t < 96) lsum[t] = 0.f;                                                      \
    const unsigned short* qhb = qhp + (long)b * NN * DM;                            \
    const unsigned short* qlb = qlp + (long)b * NN * DM;                            \
    const unsigned short* xhb = xTh + (long)b * DD * NN;                            \
    const unsigned short* xlb = xTl + (long)b * DD * NN;                            \
    short8 bh[3][2], bl[3][2];                                                      \
    _Pragma("unroll")                                                               \
    for (int rt = 0; rt < 3; ++rt) {                                                \
        _Pragma("unroll")                                                           \
        for (int kc = 0; kc < 2; ++kc) {                                            \
            long o = (long)(n0 + sr * 48 + rt * 16 + l15) * DM + kc * 32 + quad * 8;\
            bh[rt][kc] = *(const short8*)(qhb + o);                                 \
            bl[rt][kc] = *(const short8*)(qlb + o);                                 \
        }                                                                           \
    }                                                                               \
    float lp[3] = {0.f, 0.f, 0.f};                                                  \
    f32x4 acc[6][3];                                                                \
    _Pragma("unroll")                                                               \
    for (int ct = 0; ct < 6; ++ct) {                                                \
        _Pragma("unroll")                                                           \
        for (int nt = 0; nt < 3; ++nt) acc[ct][nt] = 0.f;                           \
    }

#define DMA_X(DH_, DL_, KB_) do {                                                   \
    _Pragma("unroll")                                                               \
    for (int j = 0; j < 6; ++j) {                                                   \
        int cg = w * 6 + j;                                                         \
        int cm = cg - (cg >= 12 ? 12 : 0);                                          \
        unsigned short* dstb = (cg < 12 ? (DH_) : (DL_)) + cm * 512;                \
        const unsigned short* srcb = (cg < 12 ? xhb : xlb);                         \
        int col = cm * 8 + (lane >> 3);                                             \
        int key = ((lane & 7) ^ (col & 7)) * 8;                                     \
        __builtin_amdgcn_global_load_lds(                                           \
            (const __attribute__((address_space(1))) void*)                         \
                (srcb + (long)(cb + col) * NN + (KB_) + key),                       \
            (__attribute__((address_space(3))) void*)dstb, 16, 0, 0);               \
    }                                                                               \
} while (0)

#define QPF(QN_, KQ_) do {                                                          \
    _Pragma("unroll")                                                               \
    for (int kt = 0; kt < 2; ++kt) {                                                \
        long o = (long)((KQ_) + sk * 32 + kt * 16 + l15) * DM + quad * 8;           \
        QN_[kt * 4 + 0] = *(const short8*)(qhb + o);                                \
        QN_[kt * 4 + 1] = *(const short8*)(qhb + o + 32);                           \
        QN_[kt * 4 + 2] = *(const short8*)(qlb + o);                                \
        QN_[kt * 4 + 3] = *(const short8*)(qlb + o + 32);                           \
    }                                                                               \
} while (0)

#define S_KT(QH0_, QH1_, QL0_, QL1_, KT_) do {                                      \
    _Pragma("unroll")                                                               \
    for (int rt = 0; rt < 3; ++rt) {                                                \
        f32x4 s = 0.f;                                                              \
        s = MFMA(QH0_, bh[rt][0], s);                                               \
        s = MFMA(QH1_, bh[rt][1], s);                                               \
        s = MFMA(QL0_, bh[rt][0], s);                                               \
        s = MFMA(QL1_, bh[rt][1], s);                                               \
        s = MFMA(QH0_, bl[rt][0], s);                                               \
        s = MFMA(QH1_, bl[rt][1], s);                                               \
        float p0 = __expf(s[0] * 0.125f);                                           \
        float p1 = __expf(s[1] * 0.125f);                                           \
        float p2 = __expf(s[2] * 0.125f);                                           \
        float p3 = __expf(s[3] * 0.125f);                                           \
        lp[rt] += (p0 + p1) + (p2 + p3);                                            \
        unsigned u0 = __float_as_uint(p0), u1 = __float_as_uint(p1);                \
        unsigned u2 = __float_as_uint(p2), u3 = __float_as_uint(p3);                \
        uint2v dh = { (u0 >> 16) | (u1 & 0xFFFF0000u),                              \
                      (u2 >> 16) | (u3 & 0xFFFF0000u) };                            \
        float r0 = p0 - __uint_as_float(u0 & 0xFFFF0000u);                          \
        float r1 = p1 - __uint_as_float(u1 & 0xFFFF0000u);                          \
        float r2 = p2 - __uint_as_float(u2 & 0xFFFF0000u);                          \
        float r3 = p3 - __uint_as_float(u3 & 0xFFFF0000u);                          \
        unsigned v0 = __float_as_uint(r0), v1 = __float_as_uint(r1);                \
        unsigned v2 = __float_as_uint(r2), v3 = __float_as_uint(r3);                \
        uint2v dl = { (v0 >> 16) | (v1 & 0xFFFF0000u),                              \
                      (v2 >> 16) | (v3 & 0xFFFF0000u) };                            \
        int rr_ = rt * 16 + l15;                                                    \
        int ff_ = (((rr_ & 7) ^ (rr_ >> 3)) & 7) << 2;                              \
        int ix_ = pbase + rr_ * 32 + (((KT_) * 16 + quad * 4) ^ ff_);               \
        *(uint2v*)&PHs[ix_] = dh;                                                   \
        *(uint2v*)&PLs[ix_] = dl;                                                   \
    }                                                                               \
} while (0)

#define PV_PHASE(XH_, XL_) do {                                                     \
    short8 pbh[3], pbl[3];                                                          \
    _Pragma("unroll")                                                               \
    for (int nt = 0; nt < 3; ++nt) {                                                \
        int r_ = nt * 16 + l15;                                                     \
        int ff_ = (((r_ & 7) ^ (r_ >> 3)) & 7) << 2;                                \
        int i0 = pbase + r_ * 32 + ((quad * 8) ^ ff_);                              \
        int i1 = pbase + r_ * 32 + ((quad * 8 + 4) ^ ff_);                          \
        short4v h0 = *(const short4v*)&PHs[i0];                                     \
        short4v h1 = *(const short4v*)&PHs[i1];                                     \
        short4v l0 = *(const short4v*)&PLs[i0];                                     \
        short4v l1 = *(const short4v*)&PLs[i1];                                     \
        pbh[nt] = __builtin_shufflevector(h0, h1, 0, 1, 2, 3, 4, 5, 6, 7);          \
        pbl[nt] = __builtin_shufflevector(l0, l1, 0, 1, 2, 3, 4, 5, 6, 7);          \
    }                                                                               \
    _Pragma("unroll")                                                               \
    for (int ct = 0; ct < 6; ++ct) {                                                \
        int colx = ct * 16 + l15;                                                   \
        int xk = (sk * 32 + quad * 8) ^ ((colx & 7) << 3);                          \
        short8 axh = *(const short8*)&(XH_)[colx * 64 + xk];                        \
        short8 axl = *(const short8*)&(XL_)[colx * 64 + xk];                        \
        _Pragma("unroll")                                                           \
        for (int nt = 0; nt < 3; ++nt) {                                            \
            acc[ct][nt] = MFMA(axh, pbh[nt], acc[ct][nt]);                          \
            acc[ct][nt] = MFMA(axl, pbh[nt], acc[ct][nt]);                          \
            acc[ct][nt] = MFMA(axh, pbl[nt], acc[ct][nt]);                          \
        }                                                                           \
    }                                                                               \
} while (0)

#define ATTN_EPILOGUE do {                                                          \
    _Pragma("unroll")                                                               \
    for (int rt = 0; rt < 3; ++rt) {                                                \
        float v = lp[rt];                                                           \
        v += __shfl_xor(v, 16); v += __shfl_xor(v, 32);                             \
        if (lane < 16) atomicAdd(&lsum[sr * 48 + rt * 16 + l15], v);                \
    }                                                                               \
    float* M = (float*)SMEM;                                                        \
    __syncthreads();                                                                \
    if (sk == 1) {                                                                  \
        float* Mw = M + sr * (48 * 100);                                            \
        _Pragma("unroll")                                                           \
        for (int nt = 0; nt < 3; ++nt) {                                            \
            _Pragma("unroll")                                                       \
            for (int ct = 0; ct < 6; ++ct)                                          \
                *(f32x4*)&Mw[(nt * 16 + l15) * 100 + ct * 16 + quad * 4] = acc[ct][nt]; \
        }                                                                           \
    }                                                                               \
    __syncthreads();                                                                \
    if (sk == 0) {                                                                  \
        const float* Mr = M + sr * (48 * 100);                                      \
        float* OTb = OT + (long)b * DD * NN;                                        \
        _Pragma("unroll")                                                           \
        for (int nt = 0; nt < 3; ++nt) {                                            \
            int rowl = sr * 48 + nt * 16 + l15;                                     \
            int row = n0 + rowl;                                                    \
            float linv = 1.f / lsum[rowl];                                          \
            float s1 = 0.f, s2 = 0.f;                                               \
            _Pragma("unroll")                                                       \
            for (int ct = 0; ct < 6; ++ct) {                                        \
                f32x4 pq = *(const f32x4*)&Mr[(nt * 16 + l15) * 100 + ct * 16 + quad * 4]; \
                _Pragma("unroll")                                                   \
                for (int e = 0; e < 4; ++e) {                                       \
                    float vv = (acc[ct][nt][e] + pq[e]) * linv;                     \
                    acc[ct][nt][e] = vv;                                            \
                    s1 += vv; s2 += vv * vv;                                        \
                }                                                                   \
            }                                                                       \
            s1 += __shfl_xor(s1, 16); s1 += __shfl_xor(s1, 32);                     \
            s2 += __shfl_xor(s2, 16); s2 += __shfl_xor(s2, 32);                     \
            _Pragma("unroll")                                                       \
            for (int ct = 0; ct < 6; ++ct) {                                        \
                _Pragma("unroll")                                                   \
                for (int e = 0; e < 4; ++e)                                         \
                    OTb[(long)(cb + ct * 16 + quad * 4 + e) * NN + row] = acc[ct][nt][e]; \
            }                                                                       \
            if (lane < 16) {                                                        \
                atomicAdd(&stats[((long)b * NN + row) * 2 + 0], s1);                \
                atomicAdd(&stats[((long)b * NN + row) * 2 + 1], s2);                \
            }                                                                       \
        }                                                                           \
    }                                                                               \
} while (0)

__global__ __launch_bounds__(256, 2) void attn_v0(
        const unsigned short* __restrict__ qhp, const unsigned short* __restrict__ qlp,
        const unsigned short* __restrict__ xTh, const unsigned short* __restrict__ xTl,
        float* __restrict__ OT, float* __restrict__ stats) {
    __shared__ __align__(16) unsigned char SMEM[49536];
    unsigned short* XHs = (unsigned short*)SMEM;
    unsigned short* XLs = XHs + 6144;
    unsigned short* PHs = XHs + 12288;
    unsigned short* PLs = XHs + 18432;
    float* lsum = (float*)(SMEM + 49152);
    ATTN_SETUP;
    short8 qA[8], qB[8];
    QPF(qA, 0);
    for (int kp = 0; kp < NN; kp += 128) {
        __syncthreads();
        DMA_X(XHs, XLs, kp);
        { int kq = kp + 64; QPF(qB, kq); }
        S_KT(qA[0], qA[1], qA[2], qA[3], 0);
        S_KT(qA[4], qA[5], qA[6], qA[7], 1);
        __syncthreads();
        __builtin_amdgcn_s_setprio(1);
        PV_PHASE(XHs, XLs);
        __builtin_amdgcn_s_setprio(0);
        __syncthreads();
        DMA_X(XHs, XLs, kp + 64);
        { int kq = kp + 128; if (kq >= NN) kq = 0; QPF(qA, kq); }
        S_KT(qB[0], qB[1], qB[2], qB[3], 0);
        S_KT(qB[4], qB[5], qB[6], qB[7], 1);
        __syncthreads();
        __builtin_amdgcn_s_setprio(1);
        PV_PHASE(XHs, XLs);
        __builtin_amdgcn_s_setprio(0);
    }
    ATTN_EPILOGUE;
}

// ---------- LN apply (mid layers): O^T fp32 -> split-bf16 xT ------------------------
__global__ __launch_bounds__(256) void lncvt_mid_kernel(
        const float* __restrict__ OT, const float* __restrict__ stats,
        const float* __restrict__ gamma, const float* __restrict__ beta,
        unsigned short* __restrict__ xTh, unsigned short* __restrict__ xTl) {
    int t = threadIdx.x;
    int n = blockIdx.x * 64 + (t & 63);
    int b = blockIdx.z;
    int c0 = blockIdx.y * 192 + (t >> 6);
    float s1 = stats[((long)b * NN + n) * 2 + 0];
    float s2 = stats[((long)b * NN + n) * 2 + 1];
    float mu = s1 * (1.f / 768.f);
    float rs = rsqrtf(s2 * (1.f / 768.f) - mu * mu + EPSF);
    const float* OTb = OT + (long)b * DD * NN;
    #pragma unroll 4
    for (int i = 0; i < 48; ++i) {
        int c = c0 + i * 4;
        float o = OTb[(long)c * NN + n];
        float y = (o - mu) * rs * gamma[c] + beta[c];
        unsigned short h = f2b(y);
        long idx = ((long)b * DD + c) * NN + n;
        xTh[idx] = h;
        xTl[idx] = f2b(y - b2f(h));
    }
}

// ---------- LN apply (final): O^T fp32 -> out fp32 [B][N][D] via LDS transpose ------
__global__ __launch_bounds__(256) void lncvt_final_kernel(
        const float* __restrict__ OT, const float* __restrict__ stats,
        const float* __restrict__ gamma, const float* __restrict__ beta,
        float* __restrict__ out) {
    __shared__ float T[64][65];
    int t = threadIdx.x;
    int nl = t & 63, cw = t >> 6;
    int b = blockIdx.y, n0 = blockIdx.x * 64;
    int n = n0 + nl;
    float s1 = stats[((long)b * NN + n) * 2 + 0];
    float s2 = stats[((long)b * NN + n) * 2 + 1];
    float mu = s1 * (1.f / 768.f);
    float rs = rsqrtf(s2 * (1.f / 768.f) - mu * mu + EPSF);
    const float* OTb = OT + (long)b * DD * NN;
    float* ob = out + (long)b * NN * DD;
    int row_l = t >> 2, seg = t & 3;
    for (int ct = 0; ct < 12; ++ct) {
        #pragma unroll
        for (int i = 0; i < 16; ++i) {
            int cl = cw + i * 4;
            int c = ct * 64 + cl;
            float o = OTb[(long)c * NN + n];
            T[nl][cl] = (o - mu) * rs * gamma[c] + beta[c];
        }
        __syncthreads();
        #pragma unroll
        for (int i = 0; i < 4; ++i) {
            int cl = seg * 16 + i * 4;
            float4 v = *(const float4*)&T[row_l][cl];
            *(float4*)&ob[(long)(n0 + row_l) * DD + ct * 64 + cl] = v;
        }
        __syncthreads();
    }
}

extern "C" void kernel_launch(void* const* d_in, const int* in_sizes, int n_in,
                              void* d_out, int out_size, void* d_ws, size_t ws_size,
                              hipStream_t stream) {
    (void)in_sizes; (void)n_in; (void)out_size;
    const float* x     = (const float*)d_in[0];
    const float* Wq    = (const float*)d_in[1];
    const float* bq    = (const float*)d_in[2];
    const float* gamma = (const float*)d_in[3];
    const float* beta  = (const float*)d_in[4];
    float* out = (float*)d_out;

    char* p = (char*)d_ws;
    const size_t szXT = (size_t)BB * DD * NN * 2;          // 28.3 MB
    unsigned short* xTh = (unsigned short*)p; p += szXT;
    unsigned short* xTl = (unsigned short*)p; p += szXT;
    float* OT           = (float*)p;          p += (size_t)BB * DD * NN * 4;   // 56.6 MB
    unsigned short* qh  = (unsigned short*)p; p += (size_t)BB * NN * DM * 2;
    unsigned short* ql  = (unsigned short*)p; p += (size_t)BB * NN * DM * 2;
    float* stats        = (float*)p;          p += (size_t)BB * NN * 2 * 4;
    float* lsumG        = (float*)p;          p += (size_t)BB * NN * 4;   // after stats!
    unsigned short* Wth = (unsigned short*)p; p += (size_t)DM * DD * 2;
    unsigned short* Wtl = (unsigned short*)p; p += (size_t)DM * DD * 2;

    // per-batch P (hi+lo) from the remaining workspace; choose group size gb
    size_t used = (size_t)(p - (char*)d_ws);
    const size_t perB = (size_t)NN * NN * 2 * 2;           // 21.2 MB per batch
    int gb = 0;
    if      (ws_size >= used + 8 * perB) gb = 8;
    else if (ws_size >= used + 4 * perB) gb = 4;
    else if (ws_size >= used + 2 * perB) gb = 2;
    else if (ws_size >= used + 1 * perB) gb = 1;
    unsigned short* Ph = (unsigned short*)p;
    unsigned short* Pl = Ph + (size_t)(gb > 0 ? gb : 1) * NN * NN;

    cvt_kernel<<<dim3(NN / 64, DD / 64, BB), 256, 0, stream>>>(x, xTh, xTl);
    wqcvt_kernel<<<dim3(DD * DM / 256), 256, 0, stream>>>(Wq, Wth, Wtl);

    for (int layer = 0; layer < 3; ++layer) {
        proj_kernel<<<dim3(NN / 64, BB), 256, 0, stream>>>(Wth, Wtl, xTh, xTl, bq, qh, ql);
        zstats_kernel<<<dim3(BB * NN * 3 / 256), 256, 0, stream>>>(stats); // stats+lsumG
        if (gb > 0) {
            for (int g0 = 0; g0 < BB; g0 += gb) {
                qk_kernel<<<dim3(NN / 96, 12, gb), 256, 0, stream>>>(
                    qh, ql, Ph, Pl, lsumG, g0);
                if (layer < 2)
                    pv_lds128<<<dim3((DD / 128) * (NN / 128) * gb), 256, 0, stream>>>(
                        Ph, Pl, xTh, xTl, lsumG, OT, stats, g0);
                else
                    pv_lds<<<dim3(8 * (NN / 96) * gb), 256, 0, stream>>>(
                        Ph, Pl, xTh, xTl, lsumG, OT, stats, g0);
            }
        } else {
            attn_v0<<<dim3(24 * 64), 256, 0, stream>>>(qh, ql, xTh, xTl, OT, stats);
        }
        if (layer < 2)
            lncvt_mid_kernel<<<dim3(NN / 64, 4, BB), 256, 0, stream>>>(OT, stats, gamma, beta, xTh, xTl);
        else
            lncvt_final_kernel<<<dim3(NN / 64, BB), 256, 0, stream>>>(OT, stats, gamma, beta, out);
    }
}